// Round 8
// baseline (1469.652 us; speedup 1.0000x reference)
//
#include <hip/hip_runtime.h>
#include <cstdint>
#include <cstddef>

#define N_NODES  50000
#define N_EDGES  4000
#define E_PAD    4096    // 32*128
#define NNZ_     400000
#define N_GRAPHS 64
#define C_DIM    1024
#define NBLK_BN  391
#define BN_EPS   1e-5f

typedef float f32x4  __attribute__((ext_vector_type(4)));
typedef short bf16x4 __attribute__((ext_vector_type(4)));
typedef short bf16x8 __attribute__((ext_vector_type(8)));

__device__ __forceinline__ short f2bf(float f) {
  uint32_t u = __builtin_bit_cast(uint32_t, f);
  u += 0x7fffu + ((u >> 16) & 1u);          // RNE
  return (short)(u >> 16);
}
__device__ __forceinline__ float bf2f(short s) {
  uint32_t u = ((uint32_t)(uint16_t)s) << 16;
  return __builtin_bit_cast(float, u);
}

// ---------------- CSR build ----------------
__global__ void countDeg(const int* __restrict__ ni, const int* __restrict__ ei,
                         int* __restrict__ nd, int* __restrict__ ed) {
  int i = blockIdx.x * 256 + threadIdx.x;
  if (i < NNZ_) {
    atomicAdd(&nd[ni[i]], 1);
    atomicAdd(&ed[ei[i]], 1);
  }
}

__global__ void exscan(const int* __restrict__ deg, int* __restrict__ off, int n) {
  __shared__ int wsum[16];
  __shared__ int carry_s;
  int t = threadIdx.x, lane = t & 63, w = t >> 6;
  if (t == 0) carry_s = 0;
  __syncthreads();
  for (int base = 0; base < n; base += 1024) {
    int v = (base + t < n) ? deg[base + t] : 0;
    int x = v;
    #pragma unroll
    for (int d = 1; d < 64; d <<= 1) { int y = __shfl_up(x, d); if (lane >= d) x += y; }
    if (lane == 63) wsum[w] = x;
    __syncthreads();
    if (t < 16) {
      int y = wsum[t];
      #pragma unroll
      for (int d = 1; d < 16; d <<= 1) { int z = __shfl_up(y, d); if (t >= d) y += z; }
      wsum[t] = y;
    }
    __syncthreads();
    int c = carry_s;
    int incl = x + (w ? wsum[w - 1] : 0);
    if (base + t < n) off[base + t] = c + incl - v;
    int total = wsum[15];
    __syncthreads();
    if (t == 0) carry_s = c + total;
    __syncthreads();
  }
  if (threadIdx.x == 0) off[n] = carry_s;
}

__global__ void fillCSR(const int* __restrict__ ni, const int* __restrict__ ei,
                        const int* __restrict__ noff, const int* __restrict__ eoff,
                        int* __restrict__ ncur, int* __restrict__ ecur,
                        int* __restrict__ node_edge, int* __restrict__ edge_node) {
  int i = blockIdx.x * 256 + threadIdx.x;
  if (i < NNZ_) {
    int n = ni[i], e = ei[i];
    int pe = eoff[e] + atomicAdd(&ecur[e], 1);
    edge_node[pe] = n;
    int pn = noff[n] + atomicAdd(&ncur[n], 1);
    node_edge[pn] = e;
  }
}

__global__ void invdeg(const int* __restrict__ nd, const int* __restrict__ ed,
                       float* __restrict__ Dinv, float* __restrict__ Binv) {
  int i = blockIdx.x * 256 + threadIdx.x;
  if (i < N_NODES) { int d = nd[i]; Dinv[i] = d > 0 ? 1.f / (float)d : 0.f; }
  if (i < N_EDGES) { int d = ed[i]; Binv[i] = d > 0 ? 1.f / (float)d : 0.f; }
}

// W [K][N] fp32 -> WT [N][K] bf16
__global__ void convertWT(const float* __restrict__ Wm, short* __restrict__ WT) {
  __shared__ float tile[64][65];
  int tx = threadIdx.x & 63, ty = threadIdx.x >> 6;  // ty 0..3
  int kb = blockIdx.x * 64, nb = blockIdx.y * 64;
  #pragma unroll
  for (int j = 0; j < 64; j += 4)
    tile[j + ty][tx] = Wm[(size_t)(kb + j + ty) * C_DIM + nb + tx];
  __syncthreads();
  #pragma unroll
  for (int j = 0; j < 64; j += 4)
    WT[(size_t)(nb + j + ty) * C_DIM + kb + tx] = f2bf(tile[tx][j + ty]);
}

// ---------------- convertX: fp32 -> bf16 [50000,1024] (layer-0 gather source) ----------------
__global__ void convertX(const float* __restrict__ X, short* __restrict__ Hbf) {
  size_t idx = ((size_t)blockIdx.x * 256 + threadIdx.x) * 8;
  float v[8];
  *(f32x4*)&v[0] = *(const f32x4*)&X[idx];
  *(f32x4*)&v[4] = *(const f32x4*)&X[idx + 4];
  bf16x8 ov;
  #pragma unroll
  for (int j = 0; j < 8; ++j) ov[j] = f2bf(v[j]);
  *(bf16x8*)&Hbf[idx] = ov;
}

// ---------------- phaseA: node->edge gather from bf16 source, fused BN+ReLU ----------------
template <int BN>
__global__ void phaseA_bn(const short* __restrict__ Hbf, const int* __restrict__ eoff,
                          const int* __restrict__ enode, const float* __restrict__ Binv,
                          const float* __restrict__ sc, const float* __restrict__ sh,
                          short* __restrict__ Mbf) {
  int t = threadIdx.x;
  int e = blockIdx.x * 2 + (t >> 7);
  int c = (t & 127) * 8;
  if (e >= N_EDGES) {
    bf16x8 z = {0, 0, 0, 0, 0, 0, 0, 0};
    *(bf16x8*)&Mbf[(size_t)e * C_DIM + c] = z;
    return;
  }
  float scl[8], shf[8];
  if (BN) {
    *(f32x4*)&scl[0] = *(const f32x4*)&sc[c];
    *(f32x4*)&scl[4] = *(const f32x4*)&sc[c + 4];
    *(f32x4*)&shf[0] = *(const f32x4*)&sh[c];
    *(f32x4*)&shf[4] = *(const f32x4*)&sh[c + 4];
  }
  int beg = eoff[e], end = eoff[e + 1];
  float a0[8] = {0, 0, 0, 0, 0, 0, 0, 0};
  float a1[8] = {0, 0, 0, 0, 0, 0, 0, 0};
  int i = beg;
  for (; i + 1 < end; i += 2) {
    bf16x8 v0 = *(const bf16x8*)&Hbf[(size_t)enode[i] * C_DIM + c];
    bf16x8 v1 = *(const bf16x8*)&Hbf[(size_t)enode[i + 1] * C_DIM + c];
    #pragma unroll
    for (int j = 0; j < 8; ++j) {
      float f0 = bf2f(v0[j]), f1 = bf2f(v1[j]);
      if (BN) {
        f0 = fmaxf(f0 * scl[j] + shf[j], 0.f);
        f1 = fmaxf(f1 * scl[j] + shf[j], 0.f);
      }
      a0[j] += f0;
      a1[j] += f1;
    }
  }
  if (i < end) {
    bf16x8 v = *(const bf16x8*)&Hbf[(size_t)enode[i] * C_DIM + c];
    #pragma unroll
    for (int j = 0; j < 8; ++j) {
      float f = bf2f(v[j]);
      if (BN) f = fmaxf(f * scl[j] + shf[j], 0.f);
      a0[j] += f;
    }
  }
  float bi = Binv[e];
  bf16x8 ov;
  #pragma unroll
  for (int j = 0; j < 8; ++j) ov[j] = f2bf((a0[j] + a1[j]) * bi);
  *(bf16x8*)&Mbf[(size_t)e * C_DIM + c] = ov;
}

// ---------------- GEMM: C[E_PAD,1024]bf16 = A[E_PAD,1024]bf16 x BT[1024,1024]bf16 ----------------
__global__ __launch_bounds__(256) void gemm_bf16(const short* __restrict__ A,
                                                 const short* __restrict__ BT,
                                                 short* __restrict__ Cc) {
  __shared__ __align__(16) short As[2][128 * 32];
  __shared__ __align__(16) short Bs[2][128 * 32];
  const int tid = threadIdx.x;
  const int w = tid >> 6;
  const int lane = tid & 63;
  const int bm = blockIdx.x, bn = blockIdx.y;
  const int wr = w >> 1, wc = w & 1;
  const int fr = lane & 15, kg = lane >> 4;
  const int qa = w * 2;
  const int srow = lane >> 2;        // 0..15
  const int skof = (lane & 3) * 8;   // 0,8,16,24

  f32x4 acc[4][4] = {};

  auto stage = [&](int ks, int buf) {
    #pragma unroll
    for (int c2 = 0; c2 < 2; ++c2) {
      int q = qa + c2;
      int row = q * 16 + srow;
      size_t gA = (size_t)(bm * 128 + row) * C_DIM + ks * 32 + skof;
      size_t gB = (size_t)(bn * 128 + row) * C_DIM + ks * 32 + skof;
      __builtin_amdgcn_global_load_lds(
          (__attribute__((address_space(1))) void*)(A + gA),
          (__attribute__((address_space(3))) void*)(&As[buf][q * 512]), 16, 0, 0);
      __builtin_amdgcn_global_load_lds(
          (__attribute__((address_space(1))) void*)(BT + gB),
          (__attribute__((address_space(3))) void*)(&Bs[buf][q * 512]), 16, 0, 0);
    }
  };
  auto compute = [&](int buf) {
    bf16x8 a[4], b[4];
    #pragma unroll
    for (int m = 0; m < 4; ++m)
      a[m] = *(const bf16x8*)&As[buf][(wr * 64 + m * 16 + fr) * 32 + kg * 8];
    #pragma unroll
    for (int n = 0; n < 4; ++n)
      b[n] = *(const bf16x8*)&Bs[buf][(wc * 64 + n * 16 + fr) * 32 + kg * 8];
    #pragma unroll
    for (int m = 0; m < 4; ++m)
      #pragma unroll
      for (int n = 0; n < 4; ++n)
        acc[m][n] = __builtin_amdgcn_mfma_f32_16x16x32_bf16(a[m], b[n], acc[m][n], 0, 0, 0);
  };

  stage(0, 0);
  __syncthreads();
  for (int ks = 0; ks < 31; ++ks) {
    stage(ks + 1, (ks + 1) & 1);
    compute(ks & 1);
    __syncthreads();
  }
  compute(1);

  const int row0 = bm * 128 + wr * 64 + kg * 4;
  const int col0 = bn * 128 + wc * 64 + fr;
  #pragma unroll
  for (int m = 0; m < 4; ++m) {
    #pragma unroll
    for (int n = 0; n < 4; ++n) {
      int r = row0 + m * 16, cc = col0 + n * 16;
      #pragma unroll
      for (int j = 0; j < 4; ++j)
        Cc[(size_t)(r + j) * C_DIM + cc] = f2bf(acc[m][n][j]);
    }
  }
}

// ---------------- phaseB fused with BN stats: edge->node gather of Mw bf16,
//                  writes H_pre bf16 + per-block column partial sums ----------------
__global__ void phaseB_fused(const short* __restrict__ M, const int* __restrict__ noff,
                             const int* __restrict__ nedge, const float* __restrict__ Dinv,
                             const float* __restrict__ bias, short* __restrict__ Hp,
                             float* __restrict__ ps, float* __restrict__ pq) {
  int t = threadIdx.x;
  int c = t * 4;
  int b = blockIdx.x;
  int r0 = b * 128;
  int r1 = r0 + 128 < N_NODES ? r0 + 128 : N_NODES;
  f32x4 bias4 = *(const f32x4*)&bias[c];
  f32x4 bsum = {0.f, 0.f, 0.f, 0.f}, bsq = {0.f, 0.f, 0.f, 0.f};
  for (int n = r0; n < r1; ++n) {
    int beg = noff[n], end = noff[n + 1];
    float a0[4] = {0, 0, 0, 0}, a1[4] = {0, 0, 0, 0};
    int i = beg;
    for (; i + 1 < end; i += 2) {
      bf16x4 v0 = *(const bf16x4*)&M[(size_t)nedge[i] * C_DIM + c];
      bf16x4 v1 = *(const bf16x4*)&M[(size_t)nedge[i + 1] * C_DIM + c];
      #pragma unroll
      for (int j = 0; j < 4; ++j) {
        a0[j] += bf2f(v0[j]);
        a1[j] += bf2f(v1[j]);
      }
    }
    if (i < end) {
      bf16x4 v = *(const bf16x4*)&M[(size_t)nedge[i] * C_DIM + c];
      #pragma unroll
      for (int j = 0; j < 4; ++j) a0[j] += bf2f(v[j]);
    }
    float di = Dinv[n];
    bf16x4 ob;
    f32x4 orr;
    #pragma unroll
    for (int j = 0; j < 4; ++j) {
      float o = (a0[j] + a1[j]) * di + bias4[j];
      ob[j] = f2bf(o);
      orr[j] = bf2f(ob[j]);     // stats on stored (rounded) values
    }
    *(bf16x4*)&Hp[(size_t)n * C_DIM + c] = ob;
    bsum += orr;
    bsq += orr * orr;
  }
  *(f32x4*)&ps[(size_t)b * C_DIM + c] = bsum;
  *(f32x4*)&pq[(size_t)b * C_DIM + c] = bsq;
}

__global__ void bnfinal2(const float* __restrict__ ps, const float* __restrict__ pq,
                         const float* __restrict__ g, const float* __restrict__ be,
                         float* __restrict__ scale, float* __restrict__ shift) {
  int c = blockIdx.x * 256 + threadIdx.x;
  float s = 0.f, q = 0.f;
  for (int p = 0; p < NBLK_BN; ++p) {
    s += ps[(size_t)p * C_DIM + c];
    q += pq[(size_t)p * C_DIM + c];
  }
  const float invN = 1.f / (float)N_NODES;
  float mu = s * invN;
  float var = q * invN - mu * mu;
  float rs = rsqrtf(var + BN_EPS);
  float scl = g[c] * rs;
  scale[c] = scl;
  shift[c] = be[c] - mu * scl;
}

// ---------------- final: per-row BN+ReLU+dot from bf16 H_pre ----------------
__global__ void finaldot_bf(const short* __restrict__ Hp, const float* __restrict__ sc,
                            const float* __restrict__ sh, const float* __restrict__ Wfc,
                            float* __restrict__ rows) {
  int row = blockIdx.x * 4 + (threadIdx.x >> 6);
  int lane = threadIdx.x & 63;
  if (row >= N_NODES) return;
  const short* hr = Hp + (size_t)row * C_DIM;
  float s = 0.f;
  #pragma unroll
  for (int j = 0; j < 2; ++j) {
    int c = j * 512 + lane * 8;
    bf16x8 v = *(const bf16x8*)&hr[c];
    float a[8], b[8], w[8];
    *(f32x4*)&a[0] = *(const f32x4*)&sc[c];
    *(f32x4*)&a[4] = *(const f32x4*)&sc[c + 4];
    *(f32x4*)&b[0] = *(const f32x4*)&sh[c];
    *(f32x4*)&b[4] = *(const f32x4*)&sh[c + 4];
    *(f32x4*)&w[0] = *(const f32x4*)&Wfc[c];
    *(f32x4*)&w[4] = *(const f32x4*)&Wfc[c + 4];
    #pragma unroll
    for (int k = 0; k < 8; ++k)
      s += fmaxf(bf2f(v[k]) * a[k] + b[k], 0.f) * w[k];
  }
  #pragma unroll
  for (int off = 32; off; off >>= 1) s += __shfl_down(s, off);
  if (lane == 0) rows[row] = s;
}

// batch is sorted -> LDS bins then few global atomics
__global__ void poolbin(const float* __restrict__ rows, const int* __restrict__ batch,
                        float* __restrict__ gsum, int* __restrict__ gcnt) {
  __shared__ float bins[N_GRAPHS];
  __shared__ int cbin[N_GRAPHS];
  int t = threadIdx.x;
  if (t < N_GRAPHS) { bins[t] = 0.f; cbin[t] = 0; }
  __syncthreads();
  int quad = blockIdx.x * 256 + t;            // 12500 quads = 50000 rows
  if (quad * 4 < N_NODES) {
    f32x4 r = *(const f32x4*)&rows[quad * 4];
    int4 bi = *(const int4*)&batch[quad * 4];
    int g0 = bi.x;
    float acc = r[0];
    int cc = 1;
    int gn[3] = {bi.y, bi.z, bi.w};
    float rn[3] = {r[1], r[2], r[3]};
    #pragma unroll
    for (int j = 0; j < 3; ++j) {
      if (gn[j] == g0) { acc += rn[j]; ++cc; }
      else {
        atomicAdd(&bins[g0], acc);
        atomicAdd(&cbin[g0], cc);
        g0 = gn[j]; acc = rn[j]; cc = 1;
      }
    }
    atomicAdd(&bins[g0], acc);
    atomicAdd(&cbin[g0], cc);
  }
  __syncthreads();
  if (t < N_GRAPHS && cbin[t] > 0) {
    atomicAdd(&gsum[t], bins[t]);
    atomicAdd(&gcnt[t], cbin[t]);
  }
}

__global__ void finalout(const float* __restrict__ gsum, const int* __restrict__ gcnt,
                         const float* __restrict__ bfc, float* __restrict__ out) {
  int g = threadIdx.x;
  float cnt = (float)(gcnt[g] > 0 ? gcnt[g] : 1);
  float v = gsum[g] / cnt + bfc[0];
  out[g] = 1.f / (1.f + expf(-v));
}

// ---------------- host launcher ----------------
extern "C" void kernel_launch(void* const* d_in, const int* in_sizes, int n_in,
                              void* d_out, int out_size, void* d_ws, size_t ws_size,
                              hipStream_t stream) {
  const float* x        = (const float*)d_in[0];
  const int*   node_idx = (const int*)d_in[1];
  const int*   hedge_idx= (const int*)d_in[2];
  const int*   batch    = (const int*)d_in[3];
  const float* W[3]  = {(const float*)d_in[4], (const float*)d_in[6], (const float*)d_in[8]};
  const float* bb[3] = {(const float*)d_in[5], (const float*)d_in[7], (const float*)d_in[9]};
  const float* g[3]  = {(const float*)d_in[10], (const float*)d_in[12], (const float*)d_in[14]};
  const float* be[3] = {(const float*)d_in[11], (const float*)d_in[13], (const float*)d_in[15]};
  const float* Wfc   = (const float*)d_in[16];
  const float* bfc   = (const float*)d_in[17];
  float* out = (float*)d_out;

  char* ws = (char*)d_ws;
  size_t o = 0;
  auto take = [&](size_t bytes) -> char* {
    char* p = ws + o;
    o += (bytes + 255) & ~(size_t)255;
    return p;
  };
  short* Xbf  = (short*)take((size_t)N_NODES * C_DIM * 2);  // layer-0 gather source
  short* Hp   = (short*)take((size_t)N_NODES * C_DIM * 2);  // pre-BN activations bf16
  short* Mbf  = (short*)take((size_t)E_PAD * C_DIM * 2);    // edge features bf16
  short* WT   = (short*)take((size_t)C_DIM * C_DIM * 2);
  short* Mw   = (short*)take((size_t)E_PAD * C_DIM * 2);    // (m*Binv) @ W, bf16
  char*  zgrp = take(432512);
  int*   node_deg = (int*)zgrp;
  int*   edge_deg = (int*)(zgrp + 200000);
  int*   node_cur = (int*)(zgrp + 216000);
  int*   edge_cur = (int*)(zgrp + 416000);
  float* gsum     = (float*)(zgrp + 432000);
  int*   gcnt     = (int*)(zgrp + 432256);
  int* node_off  = (int*)take((N_NODES + 1) * 4);
  int* edge_off  = (int*)take((N_EDGES + 1) * 4);
  int* node_edge = (int*)take((size_t)NNZ_ * 4);
  int* edge_node = (int*)take((size_t)NNZ_ * 4);
  float* Dinv = (float*)take(N_NODES * 4);
  float* Binv = (float*)take(N_EDGES * 4);
  float* scale = (float*)take(4096);
  float* shift = (float*)take(4096);
  float* part_s = (float*)take((size_t)NBLK_BN * C_DIM * 4);
  float* part_q = (float*)take((size_t)NBLK_BN * C_DIM * 4);
  float* rows   = (float*)take((size_t)N_NODES * 4);

  // zero atomic accumulators (must be re-zeroed every call)
  hipMemsetAsync(zgrp, 0, 432512, stream);

  // degree + CSR build
  countDeg<<<(NNZ_ + 255) / 256, 256, 0, stream>>>(node_idx, hedge_idx, node_deg, edge_deg);
  exscan<<<1, 1024, 0, stream>>>(edge_deg, edge_off, N_EDGES);
  exscan<<<1, 1024, 0, stream>>>(node_deg, node_off, N_NODES);
  fillCSR<<<(NNZ_ + 255) / 256, 256, 0, stream>>>(node_idx, hedge_idx, node_off, edge_off,
                                                  node_cur, edge_cur, node_edge, edge_node);
  invdeg<<<(N_NODES + 255) / 256, 256, 0, stream>>>(node_deg, edge_deg, Dinv, Binv);

  const int cgrid = (int)((size_t)N_NODES * C_DIM / (8 * 256));  // 25000
  convertX<<<cgrid, 256, 0, stream>>>(x, Xbf);
  for (int L = 0; L < 3; ++L) {
    if (L == 0)
      phaseA_bn<0><<<E_PAD / 2, 256, 0, stream>>>(Xbf, edge_off, edge_node, Binv,
                                                  nullptr, nullptr, Mbf);
    else
      phaseA_bn<1><<<E_PAD / 2, 256, 0, stream>>>(Hp, edge_off, edge_node, Binv,
                                                  scale, shift, Mbf);
    convertWT<<<dim3(16, 16), 256, 0, stream>>>(W[L], WT);
    gemm_bf16<<<dim3(E_PAD / 128, C_DIM / 128), 256, 0, stream>>>(Mbf, WT, Mw);
    phaseB_fused<<<NBLK_BN, 256, 0, stream>>>(Mw, node_off, node_edge, Dinv, bb[L],
                                              Hp, part_s, part_q);
    bnfinal2<<<4, 256, 0, stream>>>(part_s, part_q, g[L], be[L], scale, shift);
  }
  finaldot_bf<<<(N_NODES + 3) / 4, 256, 0, stream>>>(Hp, scale, shift, Wfc, rows);
  poolbin<<<(N_NODES / 4 + 255) / 256, 256, 0, stream>>>(rows, batch, gsum, gcnt);
  finalout<<<1, 64, 0, stream>>>(gsum, gcnt, bfc, out);
}

// Round 9
// 1120.797 us; speedup vs baseline: 1.3113x; 1.3113x over previous
//
#include <hip/hip_runtime.h>
#include <cstdint>
#include <cstddef>

#define N_NODES  50000
#define N_EDGES  4000
#define E_PAD    4096    // 32*128
#define NNZ_     400000
#define N_GRAPHS 64
#define C_DIM    1024
#define PB_BLOCKS 2048   // phaseB grid (grid-stride over nodes) -> 8192 waves
#define BN_EPS   1e-5f

typedef float f32x4  __attribute__((ext_vector_type(4)));
typedef short bf16x4 __attribute__((ext_vector_type(4)));
typedef short bf16x8 __attribute__((ext_vector_type(8)));

__device__ __forceinline__ short f2bf(float f) {
  uint32_t u = __builtin_bit_cast(uint32_t, f);
  u += 0x7fffu + ((u >> 16) & 1u);          // RNE
  return (short)(u >> 16);
}
__device__ __forceinline__ float bf2f(short s) {
  uint32_t u = ((uint32_t)(uint16_t)s) << 16;
  return __builtin_bit_cast(float, u);
}

// ---------------- CSR build ----------------
__global__ void countDeg(const int* __restrict__ ni, const int* __restrict__ ei,
                         int* __restrict__ nd, int* __restrict__ ed) {
  int i = blockIdx.x * 256 + threadIdx.x;
  if (i < NNZ_) {
    atomicAdd(&nd[ni[i]], 1);
    atomicAdd(&ed[ei[i]], 1);
  }
}

__global__ void exscan(const int* __restrict__ deg, int* __restrict__ off, int n) {
  __shared__ int wsum[16];
  __shared__ int carry_s;
  int t = threadIdx.x, lane = t & 63, w = t >> 6;
  if (t == 0) carry_s = 0;
  __syncthreads();
  for (int base = 0; base < n; base += 1024) {
    int v = (base + t < n) ? deg[base + t] : 0;
    int x = v;
    #pragma unroll
    for (int d = 1; d < 64; d <<= 1) { int y = __shfl_up(x, d); if (lane >= d) x += y; }
    if (lane == 63) wsum[w] = x;
    __syncthreads();
    if (t < 16) {
      int y = wsum[t];
      #pragma unroll
      for (int d = 1; d < 16; d <<= 1) { int z = __shfl_up(y, d); if (t >= d) y += z; }
      wsum[t] = y;
    }
    __syncthreads();
    int c = carry_s;
    int incl = x + (w ? wsum[w - 1] : 0);
    if (base + t < n) off[base + t] = c + incl - v;
    int total = wsum[15];
    __syncthreads();
    if (t == 0) carry_s = c + total;
    __syncthreads();
  }
  if (threadIdx.x == 0) off[n] = carry_s;
}

__global__ void fillCSR(const int* __restrict__ ni, const int* __restrict__ ei,
                        const int* __restrict__ noff, const int* __restrict__ eoff,
                        int* __restrict__ ncur, int* __restrict__ ecur,
                        int* __restrict__ node_edge, int* __restrict__ edge_node) {
  int i = blockIdx.x * 256 + threadIdx.x;
  if (i < NNZ_) {
    int n = ni[i], e = ei[i];
    int pe = eoff[e] + atomicAdd(&ecur[e], 1);
    edge_node[pe] = n;
    int pn = noff[n] + atomicAdd(&ncur[n], 1);
    node_edge[pn] = e;
  }
}

__global__ void invdeg(const int* __restrict__ nd, const int* __restrict__ ed,
                       float* __restrict__ Dinv, float* __restrict__ Binv) {
  int i = blockIdx.x * 256 + threadIdx.x;
  if (i < N_NODES) { int d = nd[i]; Dinv[i] = d > 0 ? 1.f / (float)d : 0.f; }
  if (i < N_EDGES) { int d = ed[i]; Binv[i] = d > 0 ? 1.f / (float)d : 0.f; }
}

// W [K][N] fp32 -> WT [N][K] bf16
__global__ void convertWT(const float* __restrict__ Wm, short* __restrict__ WT) {
  __shared__ float tile[64][65];
  int tx = threadIdx.x & 63, ty = threadIdx.x >> 6;  // ty 0..3
  int kb = blockIdx.x * 64, nb = blockIdx.y * 64;
  #pragma unroll
  for (int j = 0; j < 64; j += 4)
    tile[j + ty][tx] = Wm[(size_t)(kb + j + ty) * C_DIM + nb + tx];
  __syncthreads();
  #pragma unroll
  for (int j = 0; j < 64; j += 4)
    WT[(size_t)(nb + j + ty) * C_DIM + kb + tx] = f2bf(tile[tx][j + ty]);
}

// ---------------- convertX: fp32 -> bf16 [50000,1024] (layer-0 gather source) ----------------
__global__ void convertX(const float* __restrict__ X, short* __restrict__ Hbf) {
  size_t idx = ((size_t)blockIdx.x * 256 + threadIdx.x) * 8;
  float v[8];
  *(f32x4*)&v[0] = *(const f32x4*)&X[idx];
  *(f32x4*)&v[4] = *(const f32x4*)&X[idx + 4];
  bf16x8 ov;
  #pragma unroll
  for (int j = 0; j < 8; ++j) ov[j] = f2bf(v[j]);
  *(bf16x8*)&Hbf[idx] = ov;
}

// ---------------- phaseA: node->edge gather from bf16 source, fused BN+ReLU ----------------
template <int BN>
__global__ void phaseA_bn(const short* __restrict__ Hbf, const int* __restrict__ eoff,
                          const int* __restrict__ enode, const float* __restrict__ Binv,
                          const float* __restrict__ sc, const float* __restrict__ sh,
                          short* __restrict__ Mbf) {
  int t = threadIdx.x;
  int e = blockIdx.x * 2 + (t >> 7);
  int c = (t & 127) * 8;
  if (e >= N_EDGES) {
    bf16x8 z = {0, 0, 0, 0, 0, 0, 0, 0};
    *(bf16x8*)&Mbf[(size_t)e * C_DIM + c] = z;
    return;
  }
  float scl[8], shf[8];
  if (BN) {
    *(f32x4*)&scl[0] = *(const f32x4*)&sc[c];
    *(f32x4*)&scl[4] = *(const f32x4*)&sc[c + 4];
    *(f32x4*)&shf[0] = *(const f32x4*)&sh[c];
    *(f32x4*)&shf[4] = *(const f32x4*)&sh[c + 4];
  }
  int beg = eoff[e], end = eoff[e + 1];
  float a0[8] = {0, 0, 0, 0, 0, 0, 0, 0};
  float a1[8] = {0, 0, 0, 0, 0, 0, 0, 0};
  int i = beg;
  for (; i + 1 < end; i += 2) {
    bf16x8 v0 = *(const bf16x8*)&Hbf[(size_t)enode[i] * C_DIM + c];
    bf16x8 v1 = *(const bf16x8*)&Hbf[(size_t)enode[i + 1] * C_DIM + c];
    #pragma unroll
    for (int j = 0; j < 8; ++j) {
      float f0 = bf2f(v0[j]), f1 = bf2f(v1[j]);
      if (BN) {
        f0 = fmaxf(f0 * scl[j] + shf[j], 0.f);
        f1 = fmaxf(f1 * scl[j] + shf[j], 0.f);
      }
      a0[j] += f0;
      a1[j] += f1;
    }
  }
  if (i < end) {
    bf16x8 v = *(const bf16x8*)&Hbf[(size_t)enode[i] * C_DIM + c];
    #pragma unroll
    for (int j = 0; j < 8; ++j) {
      float f = bf2f(v[j]);
      if (BN) f = fmaxf(f * scl[j] + shf[j], 0.f);
      a0[j] += f;
    }
  }
  float bi = Binv[e];
  bf16x8 ov;
  #pragma unroll
  for (int j = 0; j < 8; ++j) ov[j] = f2bf((a0[j] + a1[j]) * bi);
  *(bf16x8*)&Mbf[(size_t)e * C_DIM + c] = ov;
}

// ---------------- GEMM: C[E_PAD,1024]bf16 = A[E_PAD,1024]bf16 x BT[1024,1024]bf16 ----------------
__global__ __launch_bounds__(256) void gemm_bf16(const short* __restrict__ A,
                                                 const short* __restrict__ BT,
                                                 short* __restrict__ Cc) {
  __shared__ __align__(16) short As[2][128 * 32];
  __shared__ __align__(16) short Bs[2][128 * 32];
  const int tid = threadIdx.x;
  const int w = tid >> 6;
  const int lane = tid & 63;
  const int bm = blockIdx.x, bn = blockIdx.y;
  const int wr = w >> 1, wc = w & 1;
  const int fr = lane & 15, kg = lane >> 4;
  const int qa = w * 2;
  const int srow = lane >> 2;        // 0..15
  const int skof = (lane & 3) * 8;   // 0,8,16,24

  f32x4 acc[4][4] = {};

  auto stage = [&](int ks, int buf) {
    #pragma unroll
    for (int c2 = 0; c2 < 2; ++c2) {
      int q = qa + c2;
      int row = q * 16 + srow;
      size_t gA = (size_t)(bm * 128 + row) * C_DIM + ks * 32 + skof;
      size_t gB = (size_t)(bn * 128 + row) * C_DIM + ks * 32 + skof;
      __builtin_amdgcn_global_load_lds(
          (__attribute__((address_space(1))) void*)(A + gA),
          (__attribute__((address_space(3))) void*)(&As[buf][q * 512]), 16, 0, 0);
      __builtin_amdgcn_global_load_lds(
          (__attribute__((address_space(1))) void*)(BT + gB),
          (__attribute__((address_space(3))) void*)(&Bs[buf][q * 512]), 16, 0, 0);
    }
  };
  auto compute = [&](int buf) {
    bf16x8 a[4], b[4];
    #pragma unroll
    for (int m = 0; m < 4; ++m)
      a[m] = *(const bf16x8*)&As[buf][(wr * 64 + m * 16 + fr) * 32 + kg * 8];
    #pragma unroll
    for (int n = 0; n < 4; ++n)
      b[n] = *(const bf16x8*)&Bs[buf][(wc * 64 + n * 16 + fr) * 32 + kg * 8];
    #pragma unroll
    for (int m = 0; m < 4; ++m)
      #pragma unroll
      for (int n = 0; n < 4; ++n)
        acc[m][n] = __builtin_amdgcn_mfma_f32_16x16x32_bf16(a[m], b[n], acc[m][n], 0, 0, 0);
  };

  stage(0, 0);
  __syncthreads();
  for (int ks = 0; ks < 31; ++ks) {
    stage(ks + 1, (ks + 1) & 1);
    compute(ks & 1);
    __syncthreads();
  }
  compute(1);

  const int row0 = bm * 128 + wr * 64 + kg * 4;
  const int col0 = bn * 128 + wc * 64 + fr;
  #pragma unroll
  for (int m = 0; m < 4; ++m) {
    #pragma unroll
    for (int n = 0; n < 4; ++n) {
      int r = row0 + m * 16, cc = col0 + n * 16;
      #pragma unroll
      for (int j = 0; j < 4; ++j)
        Cc[(size_t)(r + j) * C_DIM + cc] = f2bf(acc[m][n][j]);
    }
  }
}

// ---------------- phaseB fused with BN stats, grid-stride for full occupancy ----------------
__global__ void phaseB_fused2(const short* __restrict__ M, const int* __restrict__ noff,
                              const int* __restrict__ nedge, const float* __restrict__ Dinv,
                              const float* __restrict__ bias, short* __restrict__ Hp,
                              float* __restrict__ ps, float* __restrict__ pq) {
  int t = threadIdx.x;
  int c = t * 4;
  int b = blockIdx.x;
  f32x4 bias4 = *(const f32x4*)&bias[c];
  f32x4 bsum = {0.f, 0.f, 0.f, 0.f}, bsq = {0.f, 0.f, 0.f, 0.f};
  for (int n = b; n < N_NODES; n += PB_BLOCKS) {
    int beg = noff[n], end = noff[n + 1];
    float a0[4] = {0, 0, 0, 0}, a1[4] = {0, 0, 0, 0};
    int i = beg;
    for (; i + 1 < end; i += 2) {
      bf16x4 v0 = *(const bf16x4*)&M[(size_t)nedge[i] * C_DIM + c];
      bf16x4 v1 = *(const bf16x4*)&M[(size_t)nedge[i + 1] * C_DIM + c];
      #pragma unroll
      for (int j = 0; j < 4; ++j) {
        a0[j] += bf2f(v0[j]);
        a1[j] += bf2f(v1[j]);
      }
    }
    if (i < end) {
      bf16x4 v = *(const bf16x4*)&M[(size_t)nedge[i] * C_DIM + c];
      #pragma unroll
      for (int j = 0; j < 4; ++j) a0[j] += bf2f(v[j]);
    }
    float di = Dinv[n];
    bf16x4 ob;
    f32x4 orr;
    #pragma unroll
    for (int j = 0; j < 4; ++j) {
      float o = (a0[j] + a1[j]) * di + bias4[j];
      ob[j] = f2bf(o);
      orr[j] = bf2f(ob[j]);     // stats on stored (rounded) values
    }
    *(bf16x4*)&Hp[(size_t)n * C_DIM + c] = ob;
    bsum += orr;
    bsq += orr * orr;
  }
  *(f32x4*)&ps[(size_t)b * C_DIM + c] = bsum;
  *(f32x4*)&pq[(size_t)b * C_DIM + c] = bsq;
}

// reduce [PB_BLOCKS][1024] -> [8][1024], coalesced: block (i,j) sums 256 rows x 256 cols
__global__ void reduceP(const float* __restrict__ ps, const float* __restrict__ pq,
                        float* __restrict__ ps2, float* __restrict__ pq2) {
  int i = blockIdx.x;            // 0..7
  int c = blockIdx.y * 256 + threadIdx.x;
  float s = 0.f, q = 0.f;
  for (int p = i * 256; p < (i + 1) * 256; ++p) {
    s += ps[(size_t)p * C_DIM + c];
    q += pq[(size_t)p * C_DIM + c];
  }
  ps2[(size_t)i * C_DIM + c] = s;
  pq2[(size_t)i * C_DIM + c] = q;
}

__global__ void bnfinal2(const float* __restrict__ ps2, const float* __restrict__ pq2,
                         const float* __restrict__ g, const float* __restrict__ be,
                         float* __restrict__ scale, float* __restrict__ shift) {
  int c = blockIdx.x * 256 + threadIdx.x;
  float s = 0.f, q = 0.f;
  #pragma unroll
  for (int p = 0; p < 8; ++p) {
    s += ps2[(size_t)p * C_DIM + c];
    q += pq2[(size_t)p * C_DIM + c];
  }
  const float invN = 1.f / (float)N_NODES;
  float mu = s * invN;
  float var = q * invN - mu * mu;
  float rs = rsqrtf(var + BN_EPS);
  float scl = g[c] * rs;
  scale[c] = scl;
  shift[c] = be[c] - mu * scl;
}

// ---------------- final: per-row BN+ReLU+dot from bf16 H_pre ----------------
__global__ void finaldot_bf(const short* __restrict__ Hp, const float* __restrict__ sc,
                            const float* __restrict__ sh, const float* __restrict__ Wfc,
                            float* __restrict__ rows) {
  int row = blockIdx.x * 4 + (threadIdx.x >> 6);
  int lane = threadIdx.x & 63;
  if (row >= N_NODES) return;
  const short* hr = Hp + (size_t)row * C_DIM;
  float s = 0.f;
  #pragma unroll
  for (int j = 0; j < 2; ++j) {
    int c = j * 512 + lane * 8;
    bf16x8 v = *(const bf16x8*)&hr[c];
    float a[8], b[8], w[8];
    *(f32x4*)&a[0] = *(const f32x4*)&sc[c];
    *(f32x4*)&a[4] = *(const f32x4*)&sc[c + 4];
    *(f32x4*)&b[0] = *(const f32x4*)&sh[c];
    *(f32x4*)&b[4] = *(const f32x4*)&sh[c + 4];
    *(f32x4*)&w[0] = *(const f32x4*)&Wfc[c];
    *(f32x4*)&w[4] = *(const f32x4*)&Wfc[c + 4];
    #pragma unroll
    for (int k = 0; k < 8; ++k)
      s += fmaxf(bf2f(v[k]) * a[k] + b[k], 0.f) * w[k];
  }
  #pragma unroll
  for (int off = 32; off; off >>= 1) s += __shfl_down(s, off);
  if (lane == 0) rows[row] = s;
}

// batch is sorted -> LDS bins then few global atomics
__global__ void poolbin(const float* __restrict__ rows, const int* __restrict__ batch,
                        float* __restrict__ gsum, int* __restrict__ gcnt) {
  __shared__ float bins[N_GRAPHS];
  __shared__ int cbin[N_GRAPHS];
  int t = threadIdx.x;
  if (t < N_GRAPHS) { bins[t] = 0.f; cbin[t] = 0; }
  __syncthreads();
  int quad = blockIdx.x * 256 + t;            // 12500 quads = 50000 rows
  if (quad * 4 < N_NODES) {
    f32x4 r = *(const f32x4*)&rows[quad * 4];
    int4 bi = *(const int4*)&batch[quad * 4];
    int g0 = bi.x;
    float acc = r[0];
    int cc = 1;
    int gn[3] = {bi.y, bi.z, bi.w};
    float rn[3] = {r[1], r[2], r[3]};
    #pragma unroll
    for (int j = 0; j < 3; ++j) {
      if (gn[j] == g0) { acc += rn[j]; ++cc; }
      else {
        atomicAdd(&bins[g0], acc);
        atomicAdd(&cbin[g0], cc);
        g0 = gn[j]; acc = rn[j]; cc = 1;
      }
    }
    atomicAdd(&bins[g0], acc);
    atomicAdd(&cbin[g0], cc);
  }
  __syncthreads();
  if (t < N_GRAPHS && cbin[t] > 0) {
    atomicAdd(&gsum[t], bins[t]);
    atomicAdd(&gcnt[t], cbin[t]);
  }
}

__global__ void finalout(const float* __restrict__ gsum, const int* __restrict__ gcnt,
                         const float* __restrict__ bfc, float* __restrict__ out) {
  int g = threadIdx.x;
  float cnt = (float)(gcnt[g] > 0 ? gcnt[g] : 1);
  float v = gsum[g] / cnt + bfc[0];
  out[g] = 1.f / (1.f + expf(-v));
}

// ---------------- host launcher ----------------
extern "C" void kernel_launch(void* const* d_in, const int* in_sizes, int n_in,
                              void* d_out, int out_size, void* d_ws, size_t ws_size,
                              hipStream_t stream) {
  const float* x        = (const float*)d_in[0];
  const int*   node_idx = (const int*)d_in[1];
  const int*   hedge_idx= (const int*)d_in[2];
  const int*   batch    = (const int*)d_in[3];
  const float* W[3]  = {(const float*)d_in[4], (const float*)d_in[6], (const float*)d_in[8]};
  const float* bb[3] = {(const float*)d_in[5], (const float*)d_in[7], (const float*)d_in[9]};
  const float* g[3]  = {(const float*)d_in[10], (const float*)d_in[12], (const float*)d_in[14]};
  const float* be[3] = {(const float*)d_in[11], (const float*)d_in[13], (const float*)d_in[15]};
  const float* Wfc   = (const float*)d_in[16];
  const float* bfc   = (const float*)d_in[17];
  float* out = (float*)d_out;

  char* ws = (char*)d_ws;
  size_t o = 0;
  auto take = [&](size_t bytes) -> char* {
    char* p = ws + o;
    o += (bytes + 255) & ~(size_t)255;
    return p;
  };
  short* Xbf  = (short*)take((size_t)N_NODES * C_DIM * 2);  // layer-0 gather source
  short* Hp   = (short*)take((size_t)N_NODES * C_DIM * 2);  // pre-BN activations bf16
  short* Mbf  = (short*)take((size_t)E_PAD * C_DIM * 2);    // edge features bf16
  short* WT   = (short*)take((size_t)C_DIM * C_DIM * 2);
  short* Mw   = (short*)take((size_t)E_PAD * C_DIM * 2);    // (m*Binv) @ W, bf16
  char*  zgrp = take(432512);
  int*   node_deg = (int*)zgrp;
  int*   edge_deg = (int*)(zgrp + 200000);
  int*   node_cur = (int*)(zgrp + 216000);
  int*   edge_cur = (int*)(zgrp + 416000);
  float* gsum     = (float*)(zgrp + 432000);
  int*   gcnt     = (int*)(zgrp + 432256);
  int* node_off  = (int*)take((N_NODES + 1) * 4);
  int* edge_off  = (int*)take((N_EDGES + 1) * 4);
  int* node_edge = (int*)take((size_t)NNZ_ * 4);
  int* edge_node = (int*)take((size_t)NNZ_ * 4);
  float* Dinv = (float*)take(N_NODES * 4);
  float* Binv = (float*)take(N_EDGES * 4);
  float* scale = (float*)take(4096);
  float* shift = (float*)take(4096);
  float* part_s = (float*)take((size_t)PB_BLOCKS * C_DIM * 4);
  float* part_q = (float*)take((size_t)PB_BLOCKS * C_DIM * 4);
  float* ps2    = (float*)take((size_t)8 * C_DIM * 4);
  float* pq2    = (float*)take((size_t)8 * C_DIM * 4);
  float* rows   = (float*)take((size_t)N_NODES * 4);

  // zero atomic accumulators (must be re-zeroed every call)
  hipMemsetAsync(zgrp, 0, 432512, stream);

  // degree + CSR build
  countDeg<<<(NNZ_ + 255) / 256, 256, 0, stream>>>(node_idx, hedge_idx, node_deg, edge_deg);
  exscan<<<1, 1024, 0, stream>>>(edge_deg, edge_off, N_EDGES);
  exscan<<<1, 1024, 0, stream>>>(node_deg, node_off, N_NODES);
  fillCSR<<<(NNZ_ + 255) / 256, 256, 0, stream>>>(node_idx, hedge_idx, node_off, edge_off,
                                                  node_cur, edge_cur, node_edge, edge_node);
  invdeg<<<(N_NODES + 255) / 256, 256, 0, stream>>>(node_deg, edge_deg, Dinv, Binv);

  const int cgrid = (int)((size_t)N_NODES * C_DIM / (8 * 256));  // 25000
  convertX<<<cgrid, 256, 0, stream>>>(x, Xbf);
  for (int L = 0; L < 3; ++L) {
    if (L == 0)
      phaseA_bn<0><<<E_PAD / 2, 256, 0, stream>>>(Xbf, edge_off, edge_node, Binv,
                                                  nullptr, nullptr, Mbf);
    else
      phaseA_bn<1><<<E_PAD / 2, 256, 0, stream>>>(Hp, edge_off, edge_node, Binv,
                                                  scale, shift, Mbf);
    convertWT<<<dim3(16, 16), 256, 0, stream>>>(W[L], WT);
    gemm_bf16<<<dim3(E_PAD / 128, C_DIM / 128), 256, 0, stream>>>(Mbf, WT, Mw);
    phaseB_fused2<<<PB_BLOCKS, 256, 0, stream>>>(Mw, node_off, node_edge, Dinv, bb[L],
                                                 Hp, part_s, part_q);
    reduceP<<<dim3(8, 4), 256, 0, stream>>>(part_s, part_q, ps2, pq2);
    bnfinal2<<<4, 256, 0, stream>>>(ps2, pq2, g[L], be[L], scale, shift);
  }
  finaldot_bf<<<(N_NODES + 3) / 4, 256, 0, stream>>>(Hp, scale, shift, Wfc, rows);
  poolbin<<<(N_NODES / 4 + 255) / 256, 256, 0, stream>>>(rows, batch, gsum, gcnt);
  finalout<<<1, 64, 0, stream>>>(gsum, gcnt, bfc, out);
}

// Round 10
// 1116.441 us; speedup vs baseline: 1.3164x; 1.0039x over previous
//
#include <hip/hip_runtime.h>
#include <cstdint>
#include <cstddef>

#define N_NODES  50000
#define N_EDGES  4000
#define E_PAD    4096    // 32*128
#define NNZ_     400000
#define N_GRAPHS 64
#define C_DIM    1024
#define PB_BLOCKS 2048   // phaseB grid (grid-stride over nodes) -> 8192 waves
#define BN_EPS   1e-5f

typedef float f32x4  __attribute__((ext_vector_type(4)));
typedef short bf16x4 __attribute__((ext_vector_type(4)));
typedef short bf16x8 __attribute__((ext_vector_type(8)));

__device__ __forceinline__ short f2bf(float f) {
  uint32_t u = __builtin_bit_cast(uint32_t, f);
  u += 0x7fffu + ((u >> 16) & 1u);          // RNE
  return (short)(u >> 16);
}
__device__ __forceinline__ float bf2f(short s) {
  uint32_t u = ((uint32_t)(uint16_t)s) << 16;
  return __builtin_bit_cast(float, u);
}

// ---------------- CSR build ----------------
__global__ void countDeg(const int* __restrict__ ni, const int* __restrict__ ei,
                         int* __restrict__ nd, int* __restrict__ ed) {
  int i = blockIdx.x * 256 + threadIdx.x;
  if (i < NNZ_) {
    atomicAdd(&nd[ni[i]], 1);
    atomicAdd(&ed[ei[i]], 1);
  }
}

__global__ void exscan(const int* __restrict__ deg, int* __restrict__ off, int n) {
  __shared__ int wsum[16];
  __shared__ int carry_s;
  int t = threadIdx.x, lane = t & 63, w = t >> 6;
  if (t == 0) carry_s = 0;
  __syncthreads();
  for (int base = 0; base < n; base += 1024) {
    int v = (base + t < n) ? deg[base + t] : 0;
    int x = v;
    #pragma unroll
    for (int d = 1; d < 64; d <<= 1) { int y = __shfl_up(x, d); if (lane >= d) x += y; }
    if (lane == 63) wsum[w] = x;
    __syncthreads();
    if (t < 16) {
      int y = wsum[t];
      #pragma unroll
      for (int d = 1; d < 16; d <<= 1) { int z = __shfl_up(y, d); if (t >= d) y += z; }
      wsum[t] = y;
    }
    __syncthreads();
    int c = carry_s;
    int incl = x + (w ? wsum[w - 1] : 0);
    if (base + t < n) off[base + t] = c + incl - v;
    int total = wsum[15];
    __syncthreads();
    if (t == 0) carry_s = c + total;
    __syncthreads();
  }
  if (threadIdx.x == 0) off[n] = carry_s;
}

__global__ void fillCSR(const int* __restrict__ ni, const int* __restrict__ ei,
                        const int* __restrict__ noff, const int* __restrict__ eoff,
                        int* __restrict__ ncur, int* __restrict__ ecur,
                        int* __restrict__ node_edge, int* __restrict__ edge_node) {
  int i = blockIdx.x * 256 + threadIdx.x;
  if (i < NNZ_) {
    int n = ni[i], e = ei[i];
    int pe = eoff[e] + atomicAdd(&ecur[e], 1);
    edge_node[pe] = n;
    int pn = noff[n] + atomicAdd(&ncur[n], 1);
    node_edge[pn] = e;
  }
}

__global__ void invdeg(const int* __restrict__ nd, const int* __restrict__ ed,
                       float* __restrict__ Dinv, float* __restrict__ Binv) {
  int i = blockIdx.x * 256 + threadIdx.x;
  if (i < N_NODES) { int d = nd[i]; Dinv[i] = d > 0 ? 1.f / (float)d : 0.f; }
  if (i < N_EDGES) { int d = ed[i]; Binv[i] = d > 0 ? 1.f / (float)d : 0.f; }
}

// W [K][N] fp32 -> WT [N][K] bf16
__global__ void convertWT(const float* __restrict__ Wm, short* __restrict__ WT) {
  __shared__ float tile[64][65];
  int tx = threadIdx.x & 63, ty = threadIdx.x >> 6;  // ty 0..3
  int kb = blockIdx.x * 64, nb = blockIdx.y * 64;
  #pragma unroll
  for (int j = 0; j < 64; j += 4)
    tile[j + ty][tx] = Wm[(size_t)(kb + j + ty) * C_DIM + nb + tx];
  __syncthreads();
  #pragma unroll
  for (int j = 0; j < 64; j += 4)
    WT[(size_t)(nb + j + ty) * C_DIM + kb + tx] = f2bf(tile[tx][j + ty]);
}

// ---------------- convertX: fp32 -> bf16 [50000,1024] (layer-0 gather source) ----------------
__global__ void convertX(const float* __restrict__ X, short* __restrict__ Hbf) {
  size_t idx = ((size_t)blockIdx.x * 256 + threadIdx.x) * 8;
  float v[8];
  *(f32x4*)&v[0] = *(const f32x4*)&X[idx];
  *(f32x4*)&v[4] = *(const f32x4*)&X[idx + 4];
  bf16x8 ov;
  #pragma unroll
  for (int j = 0; j < 8; ++j) ov[j] = f2bf(v[j]);
  *(bf16x8*)&Hbf[idx] = ov;
}

// ---------------- phaseA v2: one edge per 128-thread block; LDS-staged indices,
//                  4-deep row MLP, fused BN+ReLU ----------------
template <int BN>
__global__ __launch_bounds__(128) void phaseA_bn2(
    const short* __restrict__ Hbf, const int* __restrict__ eoff,
    const int* __restrict__ enode, const float* __restrict__ Binv,
    const float* __restrict__ sc, const float* __restrict__ sh,
    short* __restrict__ Mbf) {
  __shared__ int sidx[256];
  int t = threadIdx.x;          // 0..127
  int e = blockIdx.x;
  int c = t * 8;
  int beg = 0, len = 0;
  if (e < N_EDGES) {
    beg = eoff[e];
    len = eoff[e + 1] - beg;
  }
  float scl[8], shf[8];
  if (BN) {
    *(f32x4*)&scl[0] = *(const f32x4*)&sc[c];
    *(f32x4*)&scl[4] = *(const f32x4*)&sc[c + 4];
    *(f32x4*)&shf[0] = *(const f32x4*)&sh[c];
    *(f32x4*)&shf[4] = *(const f32x4*)&sh[c + 4];
  }
  float a0[8] = {0, 0, 0, 0, 0, 0, 0, 0};
  float a1[8] = {0, 0, 0, 0, 0, 0, 0, 0};
  for (int base = 0; base < len; base += 256) {
    int cnt = len - base;
    if (cnt > 256) cnt = 256;
    for (int j = t; j < cnt; j += 128) sidx[j] = enode[beg + base + j];
    __syncthreads();
    int i = 0;
    for (; i + 3 < cnt; i += 4) {
      int n0 = sidx[i], n1 = sidx[i + 1], n2 = sidx[i + 2], n3 = sidx[i + 3];
      bf16x8 v0 = *(const bf16x8*)&Hbf[(size_t)n0 * C_DIM + c];
      bf16x8 v1 = *(const bf16x8*)&Hbf[(size_t)n1 * C_DIM + c];
      bf16x8 v2 = *(const bf16x8*)&Hbf[(size_t)n2 * C_DIM + c];
      bf16x8 v3 = *(const bf16x8*)&Hbf[(size_t)n3 * C_DIM + c];
      #pragma unroll
      for (int j = 0; j < 8; ++j) {
        float f0 = bf2f(v0[j]), f1 = bf2f(v1[j]);
        float f2 = bf2f(v2[j]), f3 = bf2f(v3[j]);
        if (BN) {
          f0 = fmaxf(f0 * scl[j] + shf[j], 0.f);
          f1 = fmaxf(f1 * scl[j] + shf[j], 0.f);
          f2 = fmaxf(f2 * scl[j] + shf[j], 0.f);
          f3 = fmaxf(f3 * scl[j] + shf[j], 0.f);
        }
        a0[j] += f0 + f2;
        a1[j] += f1 + f3;
      }
    }
    for (; i < cnt; ++i) {
      bf16x8 v = *(const bf16x8*)&Hbf[(size_t)sidx[i] * C_DIM + c];
      #pragma unroll
      for (int j = 0; j < 8; ++j) {
        float f = bf2f(v[j]);
        if (BN) f = fmaxf(f * scl[j] + shf[j], 0.f);
        a0[j] += f;
      }
    }
    __syncthreads();
  }
  float bi = (e < N_EDGES) ? Binv[e] : 0.f;
  bf16x8 ov;
  #pragma unroll
  for (int j = 0; j < 8; ++j) ov[j] = f2bf((a0[j] + a1[j]) * bi);
  *(bf16x8*)&Mbf[(size_t)e * C_DIM + c] = ov;
}

// ---------------- GEMM: C[E_PAD,1024]bf16 = A[E_PAD,1024]bf16 x BT[1024,1024]bf16 ----------------
__global__ __launch_bounds__(256) void gemm_bf16(const short* __restrict__ A,
                                                 const short* __restrict__ BT,
                                                 short* __restrict__ Cc) {
  __shared__ __align__(16) short As[2][128 * 32];
  __shared__ __align__(16) short Bs[2][128 * 32];
  const int tid = threadIdx.x;
  const int w = tid >> 6;
  const int lane = tid & 63;
  const int bm = blockIdx.x, bn = blockIdx.y;
  const int wr = w >> 1, wc = w & 1;
  const int fr = lane & 15, kg = lane >> 4;
  const int qa = w * 2;
  const int srow = lane >> 2;        // 0..15
  const int skof = (lane & 3) * 8;   // 0,8,16,24

  f32x4 acc[4][4] = {};

  auto stage = [&](int ks, int buf) {
    #pragma unroll
    for (int c2 = 0; c2 < 2; ++c2) {
      int q = qa + c2;
      int row = q * 16 + srow;
      size_t gA = (size_t)(bm * 128 + row) * C_DIM + ks * 32 + skof;
      size_t gB = (size_t)(bn * 128 + row) * C_DIM + ks * 32 + skof;
      __builtin_amdgcn_global_load_lds(
          (__attribute__((address_space(1))) void*)(A + gA),
          (__attribute__((address_space(3))) void*)(&As[buf][q * 512]), 16, 0, 0);
      __builtin_amdgcn_global_load_lds(
          (__attribute__((address_space(1))) void*)(BT + gB),
          (__attribute__((address_space(3))) void*)(&Bs[buf][q * 512]), 16, 0, 0);
    }
  };
  auto compute = [&](int buf) {
    bf16x8 a[4], b[4];
    #pragma unroll
    for (int m = 0; m < 4; ++m)
      a[m] = *(const bf16x8*)&As[buf][(wr * 64 + m * 16 + fr) * 32 + kg * 8];
    #pragma unroll
    for (int n = 0; n < 4; ++n)
      b[n] = *(const bf16x8*)&Bs[buf][(wc * 64 + n * 16 + fr) * 32 + kg * 8];
    #pragma unroll
    for (int m = 0; m < 4; ++m)
      #pragma unroll
      for (int n = 0; n < 4; ++n)
        acc[m][n] = __builtin_amdgcn_mfma_f32_16x16x32_bf16(a[m], b[n], acc[m][n], 0, 0, 0);
  };

  stage(0, 0);
  __syncthreads();
  for (int ks = 0; ks < 31; ++ks) {
    stage(ks + 1, (ks + 1) & 1);
    compute(ks & 1);
    __syncthreads();
  }
  compute(1);

  const int row0 = bm * 128 + wr * 64 + kg * 4;
  const int col0 = bn * 128 + wc * 64 + fr;
  #pragma unroll
  for (int m = 0; m < 4; ++m) {
    #pragma unroll
    for (int n = 0; n < 4; ++n) {
      int r = row0 + m * 16, cc = col0 + n * 16;
      #pragma unroll
      for (int j = 0; j < 4; ++j)
        Cc[(size_t)(r + j) * C_DIM + cc] = f2bf(acc[m][n][j]);
    }
  }
}

// ---------------- phaseB fused with BN stats, grid-stride, 4-deep MLP ----------------
__global__ void phaseB_fused3(const short* __restrict__ M, const int* __restrict__ noff,
                              const int* __restrict__ nedge, const float* __restrict__ Dinv,
                              const float* __restrict__ bias, short* __restrict__ Hp,
                              float* __restrict__ ps, float* __restrict__ pq) {
  int t = threadIdx.x;
  int c = t * 4;
  int b = blockIdx.x;
  f32x4 bias4 = *(const f32x4*)&bias[c];
  f32x4 bsum = {0.f, 0.f, 0.f, 0.f}, bsq = {0.f, 0.f, 0.f, 0.f};
  for (int n = b; n < N_NODES; n += PB_BLOCKS) {
    int beg = noff[n], end = noff[n + 1];
    float a0[4] = {0, 0, 0, 0}, a1[4] = {0, 0, 0, 0};
    int i = beg;
    for (; i + 3 < end; i += 4) {
      int e0 = nedge[i], e1 = nedge[i + 1], e2 = nedge[i + 2], e3 = nedge[i + 3];
      bf16x4 v0 = *(const bf16x4*)&M[(size_t)e0 * C_DIM + c];
      bf16x4 v1 = *(const bf16x4*)&M[(size_t)e1 * C_DIM + c];
      bf16x4 v2 = *(const bf16x4*)&M[(size_t)e2 * C_DIM + c];
      bf16x4 v3 = *(const bf16x4*)&M[(size_t)e3 * C_DIM + c];
      #pragma unroll
      for (int j = 0; j < 4; ++j) {
        a0[j] += bf2f(v0[j]) + bf2f(v2[j]);
        a1[j] += bf2f(v1[j]) + bf2f(v3[j]);
      }
    }
    for (; i < end; ++i) {
      bf16x4 v = *(const bf16x4*)&M[(size_t)nedge[i] * C_DIM + c];
      #pragma unroll
      for (int j = 0; j < 4; ++j) a0[j] += bf2f(v[j]);
    }
    float di = Dinv[n];
    bf16x4 ob;
    f32x4 orr;
    #pragma unroll
    for (int j = 0; j < 4; ++j) {
      float o = (a0[j] + a1[j]) * di + bias4[j];
      ob[j] = f2bf(o);
      orr[j] = bf2f(ob[j]);     // stats on stored (rounded) values
    }
    *(bf16x4*)&Hp[(size_t)n * C_DIM + c] = ob;
    bsum += orr;
    bsq += orr * orr;
  }
  *(f32x4*)&ps[(size_t)b * C_DIM + c] = bsum;
  *(f32x4*)&pq[(size_t)b * C_DIM + c] = bsq;
}

// reduce [PB_BLOCKS][1024] -> [8][1024], coalesced
__global__ void reduceP(const float* __restrict__ ps, const float* __restrict__ pq,
                        float* __restrict__ ps2, float* __restrict__ pq2) {
  int i = blockIdx.x;            // 0..7
  int c = blockIdx.y * 256 + threadIdx.x;
  float s = 0.f, q = 0.f;
  for (int p = i * 256; p < (i + 1) * 256; ++p) {
    s += ps[(size_t)p * C_DIM + c];
    q += pq[(size_t)p * C_DIM + c];
  }
  ps2[(size_t)i * C_DIM + c] = s;
  pq2[(size_t)i * C_DIM + c] = q;
}

__global__ void bnfinal2(const float* __restrict__ ps2, const float* __restrict__ pq2,
                         const float* __restrict__ g, const float* __restrict__ be,
                         float* __restrict__ scale, float* __restrict__ shift) {
  int c = blockIdx.x * 256 + threadIdx.x;
  float s = 0.f, q = 0.f;
  #pragma unroll
  for (int p = 0; p < 8; ++p) {
    s += ps2[(size_t)p * C_DIM + c];
    q += pq2[(size_t)p * C_DIM + c];
  }
  const float invN = 1.f / (float)N_NODES;
  float mu = s * invN;
  float var = q * invN - mu * mu;
  float rs = rsqrtf(var + BN_EPS);
  float scl = g[c] * rs;
  scale[c] = scl;
  shift[c] = be[c] - mu * scl;
}

// ---------------- final: per-row BN+ReLU+dot from bf16 H_pre ----------------
__global__ void finaldot_bf(const short* __restrict__ Hp, const float* __restrict__ sc,
                            const float* __restrict__ sh, const float* __restrict__ Wfc,
                            float* __restrict__ rows) {
  int row = blockIdx.x * 4 + (threadIdx.x >> 6);
  int lane = threadIdx.x & 63;
  if (row >= N_NODES) return;
  const short* hr = Hp + (size_t)row * C_DIM;
  float s = 0.f;
  #pragma unroll
  for (int j = 0; j < 2; ++j) {
    int c = j * 512 + lane * 8;
    bf16x8 v = *(const bf16x8*)&hr[c];
    float a[8], b[8], w[8];
    *(f32x4*)&a[0] = *(const f32x4*)&sc[c];
    *(f32x4*)&a[4] = *(const f32x4*)&sc[c + 4];
    *(f32x4*)&b[0] = *(const f32x4*)&sh[c];
    *(f32x4*)&b[4] = *(const f32x4*)&sh[c + 4];
    *(f32x4*)&w[0] = *(const f32x4*)&Wfc[c];
    *(f32x4*)&w[4] = *(const f32x4*)&Wfc[c + 4];
    #pragma unroll
    for (int k = 0; k < 8; ++k)
      s += fmaxf(bf2f(v[k]) * a[k] + b[k], 0.f) * w[k];
  }
  #pragma unroll
  for (int off = 32; off; off >>= 1) s += __shfl_down(s, off);
  if (lane == 0) rows[row] = s;
}

// batch is sorted -> LDS bins then few global atomics
__global__ void poolbin(const float* __restrict__ rows, const int* __restrict__ batch,
                        float* __restrict__ gsum, int* __restrict__ gcnt) {
  __shared__ float bins[N_GRAPHS];
  __shared__ int cbin[N_GRAPHS];
  int t = threadIdx.x;
  if (t < N_GRAPHS) { bins[t] = 0.f; cbin[t] = 0; }
  __syncthreads();
  int quad = blockIdx.x * 256 + t;            // 12500 quads = 50000 rows
  if (quad * 4 < N_NODES) {
    f32x4 r = *(const f32x4*)&rows[quad * 4];
    int4 bi = *(const int4*)&batch[quad * 4];
    int g0 = bi.x;
    float acc = r[0];
    int cc = 1;
    int gn[3] = {bi.y, bi.z, bi.w};
    float rn[3] = {r[1], r[2], r[3]};
    #pragma unroll
    for (int j = 0; j < 3; ++j) {
      if (gn[j] == g0) { acc += rn[j]; ++cc; }
      else {
        atomicAdd(&bins[g0], acc);
        atomicAdd(&cbin[g0], cc);
        g0 = gn[j]; acc = rn[j]; cc = 1;
      }
    }
    atomicAdd(&bins[g0], acc);
    atomicAdd(&cbin[g0], cc);
  }
  __syncthreads();
  if (t < N_GRAPHS && cbin[t] > 0) {
    atomicAdd(&gsum[t], bins[t]);
    atomicAdd(&gcnt[t], cbin[t]);
  }
}

__global__ void finalout(const float* __restrict__ gsum, const int* __restrict__ gcnt,
                         const float* __restrict__ bfc, float* __restrict__ out) {
  int g = threadIdx.x;
  float cnt = (float)(gcnt[g] > 0 ? gcnt[g] : 1);
  float v = gsum[g] / cnt + bfc[0];
  out[g] = 1.f / (1.f + expf(-v));
}

// ---------------- host launcher ----------------
extern "C" void kernel_launch(void* const* d_in, const int* in_sizes, int n_in,
                              void* d_out, int out_size, void* d_ws, size_t ws_size,
                              hipStream_t stream) {
  const float* x        = (const float*)d_in[0];
  const int*   node_idx = (const int*)d_in[1];
  const int*   hedge_idx= (const int*)d_in[2];
  const int*   batch    = (const int*)d_in[3];
  const float* W[3]  = {(const float*)d_in[4], (const float*)d_in[6], (const float*)d_in[8]};
  const float* bb[3] = {(const float*)d_in[5], (const float*)d_in[7], (const float*)d_in[9]};
  const float* g[3]  = {(const float*)d_in[10], (const float*)d_in[12], (const float*)d_in[14]};
  const float* be[3] = {(const float*)d_in[11], (const float*)d_in[13], (const float*)d_in[15]};
  const float* Wfc   = (const float*)d_in[16];
  const float* bfc   = (const float*)d_in[17];
  float* out = (float*)d_out;

  char* ws = (char*)d_ws;
  size_t o = 0;
  auto take = [&](size_t bytes) -> char* {
    char* p = ws + o;
    o += (bytes + 255) & ~(size_t)255;
    return p;
  };
  short* Xbf  = (short*)take((size_t)N_NODES * C_DIM * 2);  // layer-0 gather source
  short* Hp   = (short*)take((size_t)N_NODES * C_DIM * 2);  // pre-BN activations bf16
  short* Mbf  = (short*)take((size_t)E_PAD * C_DIM * 2);    // edge features bf16
  short* WT   = (short*)take((size_t)C_DIM * C_DIM * 2);
  short* Mw   = (short*)take((size_t)E_PAD * C_DIM * 2);    // (m*Binv) @ W, bf16
  char*  zgrp = take(432512);
  int*   node_deg = (int*)zgrp;
  int*   edge_deg = (int*)(zgrp + 200000);
  int*   node_cur = (int*)(zgrp + 216000);
  int*   edge_cur = (int*)(zgrp + 416000);
  float* gsum     = (float*)(zgrp + 432000);
  int*   gcnt     = (int*)(zgrp + 432256);
  int* node_off  = (int*)take((N_NODES + 1) * 4);
  int* edge_off  = (int*)take((N_EDGES + 1) * 4);
  int* node_edge = (int*)take((size_t)NNZ_ * 4);
  int* edge_node = (int*)take((size_t)NNZ_ * 4);
  float* Dinv = (float*)take(N_NODES * 4);
  float* Binv = (float*)take(N_EDGES * 4);
  float* scale = (float*)take(4096);
  float* shift = (float*)take(4096);
  float* part_s = (float*)take((size_t)PB_BLOCKS * C_DIM * 4);
  float* part_q = (float*)take((size_t)PB_BLOCKS * C_DIM * 4);
  float* ps2    = (float*)take((size_t)8 * C_DIM * 4);
  float* pq2    = (float*)take((size_t)8 * C_DIM * 4);
  float* rows   = (float*)take((size_t)N_NODES * 4);

  // zero atomic accumulators (must be re-zeroed every call)
  hipMemsetAsync(zgrp, 0, 432512, stream);

  // degree + CSR build
  countDeg<<<(NNZ_ + 255) / 256, 256, 0, stream>>>(node_idx, hedge_idx, node_deg, edge_deg);
  exscan<<<1, 1024, 0, stream>>>(edge_deg, edge_off, N_EDGES);
  exscan<<<1, 1024, 0, stream>>>(node_deg, node_off, N_NODES);
  fillCSR<<<(NNZ_ + 255) / 256, 256, 0, stream>>>(node_idx, hedge_idx, node_off, edge_off,
                                                  node_cur, edge_cur, node_edge, edge_node);
  invdeg<<<(N_NODES + 255) / 256, 256, 0, stream>>>(node_deg, edge_deg, Dinv, Binv);

  const int cgrid = (int)((size_t)N_NODES * C_DIM / (8 * 256));  // 25000
  convertX<<<cgrid, 256, 0, stream>>>(x, Xbf);
  for (int L = 0; L < 3; ++L) {
    if (L == 0)
      phaseA_bn2<0><<<E_PAD, 128, 0, stream>>>(Xbf, edge_off, edge_node, Binv,
                                               nullptr, nullptr, Mbf);
    else
      phaseA_bn2<1><<<E_PAD, 128, 0, stream>>>(Hp, edge_off, edge_node, Binv,
                                               scale, shift, Mbf);
    convertWT<<<dim3(16, 16), 256, 0, stream>>>(W[L], WT);
    gemm_bf16<<<dim3(E_PAD / 128, C_DIM / 128), 256, 0, stream>>>(Mbf, WT, Mw);
    phaseB_fused3<<<PB_BLOCKS, 256, 0, stream>>>(Mw, node_off, node_edge, Dinv, bb[L],
                                                 Hp, part_s, part_q);
    reduceP<<<dim3(8, 4), 256, 0, stream>>>(part_s, part_q, ps2, pq2);
    bnfinal2<<<4, 256, 0, stream>>>(ps2, pq2, g[L], be[L], scale, shift);
  }
  finaldot_bf<<<(N_NODES + 3) / 4, 256, 0, stream>>>(Hp, scale, shift, Wfc, rows);
  poolbin<<<(N_NODES / 4 + 255) / 256, 256, 0, stream>>>(rows, batch, gsum, gcnt);
  finalout<<<1, 64, 0, stream>>>(gsum, gcnt, bfc, out);
}

// Round 11
// 1113.829 us; speedup vs baseline: 1.3195x; 1.0023x over previous
//
#include <hip/hip_runtime.h>
#include <cstdint>
#include <cstddef>

#define N_NODES  50000
#define N_EDGES  4000
#define E_PAD    4096    // 32*128
#define NNZ_     400000
#define N_GRAPHS 64
#define C_DIM    1024
#define HALF_C   512
#define PB_BLOCKS 2048   // phaseB grid (grid-stride over nodes) -> 8192 waves
#define BN_EPS   1e-5f

typedef float f32x4  __attribute__((ext_vector_type(4)));
typedef short bf16x4 __attribute__((ext_vector_type(4)));
typedef short bf16x8 __attribute__((ext_vector_type(8)));

__device__ __forceinline__ short f2bf(float f) {
  uint32_t u = __builtin_bit_cast(uint32_t, f);
  u += 0x7fffu + ((u >> 16) & 1u);          // RNE
  return (short)(u >> 16);
}
__device__ __forceinline__ float bf2f(short s) {
  uint32_t u = ((uint32_t)(uint16_t)s) << 16;
  return __builtin_bit_cast(float, u);
}

// ---------------- CSR build ----------------
__global__ void countDeg(const int* __restrict__ ni, const int* __restrict__ ei,
                         int* __restrict__ nd, int* __restrict__ ed) {
  int i = blockIdx.x * 256 + threadIdx.x;
  if (i < NNZ_) {
    atomicAdd(&nd[ni[i]], 1);
    atomicAdd(&ed[ei[i]], 1);
  }
}

__global__ void exscan(const int* __restrict__ deg, int* __restrict__ off, int n) {
  __shared__ int wsum[16];
  __shared__ int carry_s;
  int t = threadIdx.x, lane = t & 63, w = t >> 6;
  if (t == 0) carry_s = 0;
  __syncthreads();
  for (int base = 0; base < n; base += 1024) {
    int v = (base + t < n) ? deg[base + t] : 0;
    int x = v;
    #pragma unroll
    for (int d = 1; d < 64; d <<= 1) { int y = __shfl_up(x, d); if (lane >= d) x += y; }
    if (lane == 63) wsum[w] = x;
    __syncthreads();
    if (t < 16) {
      int y = wsum[t];
      #pragma unroll
      for (int d = 1; d < 16; d <<= 1) { int z = __shfl_up(y, d); if (t >= d) y += z; }
      wsum[t] = y;
    }
    __syncthreads();
    int c = carry_s;
    int incl = x + (w ? wsum[w - 1] : 0);
    if (base + t < n) off[base + t] = c + incl - v;
    int total = wsum[15];
    __syncthreads();
    if (t == 0) carry_s = c + total;
    __syncthreads();
  }
  if (threadIdx.x == 0) off[n] = carry_s;
}

__global__ void fillCSR(const int* __restrict__ ni, const int* __restrict__ ei,
                        const int* __restrict__ noff, const int* __restrict__ eoff,
                        int* __restrict__ ncur, int* __restrict__ ecur,
                        int* __restrict__ node_edge, int* __restrict__ edge_node) {
  int i = blockIdx.x * 256 + threadIdx.x;
  if (i < NNZ_) {
    int n = ni[i], e = ei[i];
    int pe = eoff[e] + atomicAdd(&ecur[e], 1);
    edge_node[pe] = n;
    int pn = noff[n] + atomicAdd(&ncur[n], 1);
    node_edge[pn] = e;
  }
}

__global__ void invdeg(const int* __restrict__ nd, const int* __restrict__ ed,
                       float* __restrict__ Dinv, float* __restrict__ Binv) {
  int i = blockIdx.x * 256 + threadIdx.x;
  if (i < N_NODES) { int d = nd[i]; Dinv[i] = d > 0 ? 1.f / (float)d : 0.f; }
  if (i < N_EDGES) { int d = ed[i]; Binv[i] = d > 0 ? 1.f / (float)d : 0.f; }
}

// W [K][N] fp32 -> WT [N][K] bf16
__global__ void convertWT(const float* __restrict__ Wm, short* __restrict__ WT) {
  __shared__ float tile[64][65];
  int tx = threadIdx.x & 63, ty = threadIdx.x >> 6;  // ty 0..3
  int kb = blockIdx.x * 64, nb = blockIdx.y * 64;
  #pragma unroll
  for (int j = 0; j < 64; j += 4)
    tile[j + ty][tx] = Wm[(size_t)(kb + j + ty) * C_DIM + nb + tx];
  __syncthreads();
  #pragma unroll
  for (int j = 0; j < 64; j += 4)
    WT[(size_t)(nb + j + ty) * C_DIM + kb + tx] = f2bf(tile[tx][j + ty]);
}

// ---------------- convertX: fp32 -> bf16 column-blocked [2][N][512] ----------------
__global__ void convertX(const float* __restrict__ X, short* __restrict__ Hbf) {
  size_t idx = ((size_t)blockIdx.x * 256 + threadIdx.x) * 8;
  int node = (int)(idx >> 10);
  int c = (int)(idx & 1023);
  int half = c >> 9, off = c & 511;
  float v[8];
  *(f32x4*)&v[0] = *(const f32x4*)&X[idx];
  *(f32x4*)&v[4] = *(const f32x4*)&X[idx + 4];
  bf16x8 ov;
  #pragma unroll
  for (int j = 0; j < 8; ++j) ov[j] = f2bf(v[j]);
  *(bf16x8*)&Hbf[((size_t)half * N_NODES + node) * HALF_C + off] = ov;
}

// ---------------- phaseA v3: one edge per 64-thread wave, column-half pass,
//                  blocked source, fused BN+ReLU ----------------
template <int BN>
__global__ __launch_bounds__(64) void phaseA_bn3(
    const short* __restrict__ Hbf, const int* __restrict__ eoff,
    const int* __restrict__ enode, const float* __restrict__ Binv,
    const float* __restrict__ sc, const float* __restrict__ sh,
    short* __restrict__ Mbf, int half) {
  int t = threadIdx.x;            // 0..63
  int e = blockIdx.x;
  int off = t * 8;                // col within half
  int gc = half * HALF_C + off;   // global col
  if (e >= N_EDGES) {
    bf16x8 z = {0, 0, 0, 0, 0, 0, 0, 0};
    *(bf16x8*)&Mbf[(size_t)e * C_DIM + gc] = z;
    return;
  }
  const short* __restrict__ src = Hbf + (size_t)half * N_NODES * HALF_C;
  float scl[8], shf[8];
  if (BN) {
    *(f32x4*)&scl[0] = *(const f32x4*)&sc[gc];
    *(f32x4*)&scl[4] = *(const f32x4*)&sc[gc + 4];
    *(f32x4*)&shf[0] = *(const f32x4*)&sh[gc];
    *(f32x4*)&shf[4] = *(const f32x4*)&sh[gc + 4];
  }
  int beg = eoff[e], end = eoff[e + 1];
  float a0[8] = {0, 0, 0, 0, 0, 0, 0, 0};
  float a1[8] = {0, 0, 0, 0, 0, 0, 0, 0};
  int i = beg;
  for (; i + 3 < end; i += 4) {
    int n0 = enode[i], n1 = enode[i + 1], n2 = enode[i + 2], n3 = enode[i + 3];
    bf16x8 v0 = *(const bf16x8*)&src[(size_t)n0 * HALF_C + off];
    bf16x8 v1 = *(const bf16x8*)&src[(size_t)n1 * HALF_C + off];
    bf16x8 v2 = *(const bf16x8*)&src[(size_t)n2 * HALF_C + off];
    bf16x8 v3 = *(const bf16x8*)&src[(size_t)n3 * HALF_C + off];
    #pragma unroll
    for (int j = 0; j < 8; ++j) {
      float f0 = bf2f(v0[j]), f1 = bf2f(v1[j]);
      float f2 = bf2f(v2[j]), f3 = bf2f(v3[j]);
      if (BN) {
        f0 = fmaxf(f0 * scl[j] + shf[j], 0.f);
        f1 = fmaxf(f1 * scl[j] + shf[j], 0.f);
        f2 = fmaxf(f2 * scl[j] + shf[j], 0.f);
        f3 = fmaxf(f3 * scl[j] + shf[j], 0.f);
      }
      a0[j] += f0 + f2;
      a1[j] += f1 + f3;
    }
  }
  for (; i < end; ++i) {
    bf16x8 v = *(const bf16x8*)&src[(size_t)enode[i] * HALF_C + off];
    #pragma unroll
    for (int j = 0; j < 8; ++j) {
      float f = bf2f(v[j]);
      if (BN) f = fmaxf(f * scl[j] + shf[j], 0.f);
      a0[j] += f;
    }
  }
  float bi = Binv[e];
  bf16x8 ov;
  #pragma unroll
  for (int j = 0; j < 8; ++j) ov[j] = f2bf((a0[j] + a1[j]) * bi);
  *(bf16x8*)&Mbf[(size_t)e * C_DIM + gc] = ov;
}

// ---------------- GEMM: C[E_PAD,1024]bf16 = A[E_PAD,1024]bf16 x BT[1024,1024]bf16 ----------------
__global__ __launch_bounds__(256) void gemm_bf16(const short* __restrict__ A,
                                                 const short* __restrict__ BT,
                                                 short* __restrict__ Cc) {
  __shared__ __align__(16) short As[2][128 * 32];
  __shared__ __align__(16) short Bs[2][128 * 32];
  const int tid = threadIdx.x;
  const int w = tid >> 6;
  const int lane = tid & 63;
  const int bm = blockIdx.x, bn = blockIdx.y;
  const int wr = w >> 1, wc = w & 1;
  const int fr = lane & 15, kg = lane >> 4;
  const int qa = w * 2;
  const int srow = lane >> 2;        // 0..15
  const int skof = (lane & 3) * 8;   // 0,8,16,24

  f32x4 acc[4][4] = {};

  auto stage = [&](int ks, int buf) {
    #pragma unroll
    for (int c2 = 0; c2 < 2; ++c2) {
      int q = qa + c2;
      int row = q * 16 + srow;
      size_t gA = (size_t)(bm * 128 + row) * C_DIM + ks * 32 + skof;
      size_t gB = (size_t)(bn * 128 + row) * C_DIM + ks * 32 + skof;
      __builtin_amdgcn_global_load_lds(
          (__attribute__((address_space(1))) void*)(A + gA),
          (__attribute__((address_space(3))) void*)(&As[buf][q * 512]), 16, 0, 0);
      __builtin_amdgcn_global_load_lds(
          (__attribute__((address_space(1))) void*)(BT + gB),
          (__attribute__((address_space(3))) void*)(&Bs[buf][q * 512]), 16, 0, 0);
    }
  };
  auto compute = [&](int buf) {
    bf16x8 a[4], b[4];
    #pragma unroll
    for (int m = 0; m < 4; ++m)
      a[m] = *(const bf16x8*)&As[buf][(wr * 64 + m * 16 + fr) * 32 + kg * 8];
    #pragma unroll
    for (int n = 0; n < 4; ++n)
      b[n] = *(const bf16x8*)&Bs[buf][(wc * 64 + n * 16 + fr) * 32 + kg * 8];
    #pragma unroll
    for (int m = 0; m < 4; ++m)
      #pragma unroll
      for (int n = 0; n < 4; ++n)
        acc[m][n] = __builtin_amdgcn_mfma_f32_16x16x32_bf16(a[m], b[n], acc[m][n], 0, 0, 0);
  };

  stage(0, 0);
  __syncthreads();
  for (int ks = 0; ks < 31; ++ks) {
    stage(ks + 1, (ks + 1) & 1);
    compute(ks & 1);
    __syncthreads();
  }
  compute(1);

  const int row0 = bm * 128 + wr * 64 + kg * 4;
  const int col0 = bn * 128 + wc * 64 + fr;
  #pragma unroll
  for (int m = 0; m < 4; ++m) {
    #pragma unroll
    for (int n = 0; n < 4; ++n) {
      int r = row0 + m * 16, cc = col0 + n * 16;
      #pragma unroll
      for (int j = 0; j < 4; ++j)
        Cc[(size_t)(r + j) * C_DIM + cc] = f2bf(acc[m][n][j]);
    }
  }
}

// ---------------- phaseB fused with BN stats, grid-stride, 4-deep MLP,
//                  writes Hp in column-blocked layout ----------------
__global__ void phaseB_fused3(const short* __restrict__ M, const int* __restrict__ noff,
                              const int* __restrict__ nedge, const float* __restrict__ Dinv,
                              const float* __restrict__ bias, short* __restrict__ Hp,
                              float* __restrict__ ps, float* __restrict__ pq) {
  int t = threadIdx.x;
  int c = t * 4;
  int half = c >> 9, off = c & 511;
  short* __restrict__ Hdst = Hp + (size_t)half * N_NODES * HALF_C;
  int b = blockIdx.x;
  f32x4 bias4 = *(const f32x4*)&bias[c];
  f32x4 bsum = {0.f, 0.f, 0.f, 0.f}, bsq = {0.f, 0.f, 0.f, 0.f};
  for (int n = b; n < N_NODES; n += PB_BLOCKS) {
    int beg = noff[n], end = noff[n + 1];
    float a0[4] = {0, 0, 0, 0}, a1[4] = {0, 0, 0, 0};
    int i = beg;
    for (; i + 3 < end; i += 4) {
      int e0 = nedge[i], e1 = nedge[i + 1], e2 = nedge[i + 2], e3 = nedge[i + 3];
      bf16x4 v0 = *(const bf16x4*)&M[(size_t)e0 * C_DIM + c];
      bf16x4 v1 = *(const bf16x4*)&M[(size_t)e1 * C_DIM + c];
      bf16x4 v2 = *(const bf16x4*)&M[(size_t)e2 * C_DIM + c];
      bf16x4 v3 = *(const bf16x4*)&M[(size_t)e3 * C_DIM + c];
      #pragma unroll
      for (int j = 0; j < 4; ++j) {
        a0[j] += bf2f(v0[j]) + bf2f(v2[j]);
        a1[j] += bf2f(v1[j]) + bf2f(v3[j]);
      }
    }
    for (; i < end; ++i) {
      bf16x4 v = *(const bf16x4*)&M[(size_t)nedge[i] * C_DIM + c];
      #pragma unroll
      for (int j = 0; j < 4; ++j) a0[j] += bf2f(v[j]);
    }
    float di = Dinv[n];
    bf16x4 ob;
    f32x4 orr;
    #pragma unroll
    for (int j = 0; j < 4; ++j) {
      float o = (a0[j] + a1[j]) * di + bias4[j];
      ob[j] = f2bf(o);
      orr[j] = bf2f(ob[j]);     // stats on stored (rounded) values
    }
    *(bf16x4*)&Hdst[(size_t)n * HALF_C + off] = ob;
    bsum += orr;
    bsq += orr * orr;
  }
  *(f32x4*)&ps[(size_t)b * C_DIM + c] = bsum;
  *(f32x4*)&pq[(size_t)b * C_DIM + c] = bsq;
}

// reduce [PB_BLOCKS][1024] -> [8][1024], coalesced
__global__ void reduceP(const float* __restrict__ ps, const float* __restrict__ pq,
                        float* __restrict__ ps2, float* __restrict__ pq2) {
  int i = blockIdx.x;            // 0..7
  int c = blockIdx.y * 256 + threadIdx.x;
  float s = 0.f, q = 0.f;
  for (int p = i * 256; p < (i + 1) * 256; ++p) {
    s += ps[(size_t)p * C_DIM + c];
    q += pq[(size_t)p * C_DIM + c];
  }
  ps2[(size_t)i * C_DIM + c] = s;
  pq2[(size_t)i * C_DIM + c] = q;
}

__global__ void bnfinal2(const float* __restrict__ ps2, const float* __restrict__ pq2,
                         const float* __restrict__ g, const float* __restrict__ be,
                         float* __restrict__ scale, float* __restrict__ shift) {
  int c = blockIdx.x * 256 + threadIdx.x;
  float s = 0.f, q = 0.f;
  #pragma unroll
  for (int p = 0; p < 8; ++p) {
    s += ps2[(size_t)p * C_DIM + c];
    q += pq2[(size_t)p * C_DIM + c];
  }
  const float invN = 1.f / (float)N_NODES;
  float mu = s * invN;
  float var = q * invN - mu * mu;
  float rs = rsqrtf(var + BN_EPS);
  float scl = g[c] * rs;
  scale[c] = scl;
  shift[c] = be[c] - mu * scl;
}

// ---------------- final: per-row BN+ReLU+dot from blocked bf16 H_pre ----------------
__global__ void finaldot_bf(const short* __restrict__ Hp, const float* __restrict__ sc,
                            const float* __restrict__ sh, const float* __restrict__ Wfc,
                            float* __restrict__ rows) {
  int row = blockIdx.x * 4 + (threadIdx.x >> 6);
  int lane = threadIdx.x & 63;
  if (row >= N_NODES) return;
  float s = 0.f;
  #pragma unroll
  for (int j = 0; j < 2; ++j) {
    int c = j * HALF_C + lane * 8;
    bf16x8 v = *(const bf16x8*)&Hp[((size_t)j * N_NODES + row) * HALF_C + lane * 8];
    float a[8], b[8], w[8];
    *(f32x4*)&a[0] = *(const f32x4*)&sc[c];
    *(f32x4*)&a[4] = *(const f32x4*)&sc[c + 4];
    *(f32x4*)&b[0] = *(const f32x4*)&sh[c];
    *(f32x4*)&b[4] = *(const f32x4*)&sh[c + 4];
    *(f32x4*)&w[0] = *(const f32x4*)&Wfc[c];
    *(f32x4*)&w[4] = *(const f32x4*)&Wfc[c + 4];
    #pragma unroll
    for (int k = 0; k < 8; ++k)
      s += fmaxf(bf2f(v[k]) * a[k] + b[k], 0.f) * w[k];
  }
  #pragma unroll
  for (int off = 32; off; off >>= 1) s += __shfl_down(s, off);
  if (lane == 0) rows[row] = s;
}

// batch is sorted -> LDS bins then few global atomics
__global__ void poolbin(const float* __restrict__ rows, const int* __restrict__ batch,
                        float* __restrict__ gsum, int* __restrict__ gcnt) {
  __shared__ float bins[N_GRAPHS];
  __shared__ int cbin[N_GRAPHS];
  int t = threadIdx.x;
  if (t < N_GRAPHS) { bins[t] = 0.f; cbin[t] = 0; }
  __syncthreads();
  int quad = blockIdx.x * 256 + t;            // 12500 quads = 50000 rows
  if (quad * 4 < N_NODES) {
    f32x4 r = *(const f32x4*)&rows[quad * 4];
    int4 bi = *(const int4*)&batch[quad * 4];
    int g0 = bi.x;
    float acc = r[0];
    int cc = 1;
    int gn[3] = {bi.y, bi.z, bi.w};
    float rn[3] = {r[1], r[2], r[3]};
    #pragma unroll
    for (int j = 0; j < 3; ++j) {
      if (gn[j] == g0) { acc += rn[j]; ++cc; }
      else {
        atomicAdd(&bins[g0], acc);
        atomicAdd(&cbin[g0], cc);
        g0 = gn[j]; acc = rn[j]; cc = 1;
      }
    }
    atomicAdd(&bins[g0], acc);
    atomicAdd(&cbin[g0], cc);
  }
  __syncthreads();
  if (t < N_GRAPHS && cbin[t] > 0) {
    atomicAdd(&gsum[t], bins[t]);
    atomicAdd(&gcnt[t], cbin[t]);
  }
}

__global__ void finalout(const float* __restrict__ gsum, const int* __restrict__ gcnt,
                         const float* __restrict__ bfc, float* __restrict__ out) {
  int g = threadIdx.x;
  float cnt = (float)(gcnt[g] > 0 ? gcnt[g] : 1);
  float v = gsum[g] / cnt + bfc[0];
  out[g] = 1.f / (1.f + expf(-v));
}

// ---------------- host launcher ----------------
extern "C" void kernel_launch(void* const* d_in, const int* in_sizes, int n_in,
                              void* d_out, int out_size, void* d_ws, size_t ws_size,
                              hipStream_t stream) {
  const float* x        = (const float*)d_in[0];
  const int*   node_idx = (const int*)d_in[1];
  const int*   hedge_idx= (const int*)d_in[2];
  const int*   batch    = (const int*)d_in[3];
  const float* W[3]  = {(const float*)d_in[4], (const float*)d_in[6], (const float*)d_in[8]};
  const float* bb[3] = {(const float*)d_in[5], (const float*)d_in[7], (const float*)d_in[9]};
  const float* g[3]  = {(const float*)d_in[10], (const float*)d_in[12], (const float*)d_in[14]};
  const float* be[3] = {(const float*)d_in[11], (const float*)d_in[13], (const float*)d_in[15]};
  const float* Wfc   = (const float*)d_in[16];
  const float* bfc   = (const float*)d_in[17];
  float* out = (float*)d_out;

  char* ws = (char*)d_ws;
  size_t o = 0;
  auto take = [&](size_t bytes) -> char* {
    char* p = ws + o;
    o += (bytes + 255) & ~(size_t)255;
    return p;
  };
  short* Xbf  = (short*)take((size_t)N_NODES * C_DIM * 2);  // layer-0 source, blocked
  short* Hp   = (short*)take((size_t)N_NODES * C_DIM * 2);  // pre-BN activations, blocked
  short* Mbf  = (short*)take((size_t)E_PAD * C_DIM * 2);    // edge features bf16
  short* WT   = (short*)take((size_t)C_DIM * C_DIM * 2);
  short* Mw   = (short*)take((size_t)E_PAD * C_DIM * 2);    // (m*Binv) @ W, bf16
  char*  zgrp = take(432512);
  int*   node_deg = (int*)zgrp;
  int*   edge_deg = (int*)(zgrp + 200000);
  int*   node_cur = (int*)(zgrp + 216000);
  int*   edge_cur = (int*)(zgrp + 416000);
  float* gsum     = (float*)(zgrp + 432000);
  int*   gcnt     = (int*)(zgrp + 432256);
  int* node_off  = (int*)take((N_NODES + 1) * 4);
  int* edge_off  = (int*)take((N_EDGES + 1) * 4);
  int* node_edge = (int*)take((size_t)NNZ_ * 4);
  int* edge_node = (int*)take((size_t)NNZ_ * 4);
  float* Dinv = (float*)take(N_NODES * 4);
  float* Binv = (float*)take(N_EDGES * 4);
  float* scale = (float*)take(4096);
  float* shift = (float*)take(4096);
  float* part_s = (float*)take((size_t)PB_BLOCKS * C_DIM * 4);
  float* part_q = (float*)take((size_t)PB_BLOCKS * C_DIM * 4);
  float* ps2    = (float*)take((size_t)8 * C_DIM * 4);
  float* pq2    = (float*)take((size_t)8 * C_DIM * 4);
  float* rows   = (float*)take((size_t)N_NODES * 4);

  // zero atomic accumulators (must be re-zeroed every call)
  hipMemsetAsync(zgrp, 0, 432512, stream);

  // degree + CSR build
  countDeg<<<(NNZ_ + 255) / 256, 256, 0, stream>>>(node_idx, hedge_idx, node_deg, edge_deg);
  exscan<<<1, 1024, 0, stream>>>(edge_deg, edge_off, N_EDGES);
  exscan<<<1, 1024, 0, stream>>>(node_deg, node_off, N_NODES);
  fillCSR<<<(NNZ_ + 255) / 256, 256, 0, stream>>>(node_idx, hedge_idx, node_off, edge_off,
                                                  node_cur, edge_cur, node_edge, edge_node);
  invdeg<<<(N_NODES + 255) / 256, 256, 0, stream>>>(node_deg, edge_deg, Dinv, Binv);

  const int cgrid = (int)((size_t)N_NODES * C_DIM / (8 * 256));  // 25000
  convertX<<<cgrid, 256, 0, stream>>>(x, Xbf);
  for (int L = 0; L < 3; ++L) {
    const short* src = (L == 0) ? Xbf : Hp;
    for (int half = 0; half < 2; ++half) {
      if (L == 0)
        phaseA_bn3<0><<<E_PAD, 64, 0, stream>>>(src, edge_off, edge_node, Binv,
                                                nullptr, nullptr, Mbf, half);
      else
        phaseA_bn3<1><<<E_PAD, 64, 0, stream>>>(src, edge_off, edge_node, Binv,
                                                scale, shift, Mbf, half);
    }
    convertWT<<<dim3(16, 16), 256, 0, stream>>>(W[L], WT);
    gemm_bf16<<<dim3(E_PAD / 128, C_DIM / 128), 256, 0, stream>>>(Mbf, WT, Mw);
    phaseB_fused3<<<PB_BLOCKS, 256, 0, stream>>>(Mw, node_off, node_edge, Dinv, bb[L],
                                                 Hp, part_s, part_q);
    reduceP<<<dim3(8, 4), 256, 0, stream>>>(part_s, part_q, ps2, pq2);
    bnfinal2<<<4, 256, 0, stream>>>(ps2, pq2, g[L], be[L], scale, shift);
  }
  finaldot_bf<<<(N_NODES + 3) / 4, 256, 0, stream>>>(Hp, scale, shift, Wfc, rows);
  poolbin<<<(N_NODES / 4 + 255) / 256, 256, 0, stream>>>(rows, batch, gsum, gcnt);
  finalout<<<1, 64, 0, stream>>>(gsum, gcnt, bfc, out);
}

// Round 12
// 1071.002 us; speedup vs baseline: 1.3722x; 1.0400x over previous
//
#include <hip/hip_runtime.h>
#include <cstdint>
#include <cstddef>

#define N_NODES  50000
#define N_EDGES  4000
#define E_PAD    4096    // 32*128
#define NNZ_     400000
#define N_GRAPHS 64
#define C_DIM    1024
#define HALF_C   512
#define PB_BLOCKS 2048   // phaseB grid (grid-stride over nodes) -> 8192 waves
#define BN_EPS   1e-5f

typedef float f32x4  __attribute__((ext_vector_type(4)));
typedef short bf16x4 __attribute__((ext_vector_type(4)));
typedef short bf16x8 __attribute__((ext_vector_type(8)));

__device__ __forceinline__ short f2bf(float f) {
  uint32_t u = __builtin_bit_cast(uint32_t, f);
  u += 0x7fffu + ((u >> 16) & 1u);          // RNE
  return (short)(u >> 16);
}
__device__ __forceinline__ float bf2f(short s) {
  uint32_t u = ((uint32_t)(uint16_t)s) << 16;
  return __builtin_bit_cast(float, u);
}

// ---------------- CSR build ----------------
__global__ void countDeg(const int* __restrict__ ni, const int* __restrict__ ei,
                         int* __restrict__ nd, int* __restrict__ ed) {
  int i = blockIdx.x * 256 + threadIdx.x;
  if (i < NNZ_) {
    atomicAdd(&nd[ni[i]], 1);
    atomicAdd(&ed[ei[i]], 1);
  }
}

// ---- parallel exclusive scan: 1024 elems/block, <=64 blocks ----
__global__ void scan_part(const int* __restrict__ deg, int* __restrict__ bsum, int n) {
  __shared__ int ws[4];
  int b = blockIdx.x, t = threadIdx.x;
  int base = b * 1024 + t * 4;
  int s = 0;
  #pragma unroll
  for (int k = 0; k < 4; ++k) {
    int i = base + k;
    if (i < n) s += deg[i];
  }
  #pragma unroll
  for (int d = 32; d; d >>= 1) s += __shfl_down(s, d);
  int lane = t & 63, w = t >> 6;
  if (lane == 0) ws[w] = s;
  __syncthreads();
  if (t == 0) bsum[b] = ws[0] + ws[1] + ws[2] + ws[3];
}

__global__ void scan_mid(int* __restrict__ bsum, int nb, int* __restrict__ off, int n) {
  int t = threadIdx.x;                      // 64 threads
  int v = (t < nb) ? bsum[t] : 0;
  int orig = v;
  #pragma unroll
  for (int d = 1; d < 64; d <<= 1) { int y = __shfl_up(v, d); if (t >= d) v += y; }
  if (t < nb) bsum[t] = v - orig;           // exclusive block offsets
  if (t == 63) off[n] = v;                  // total
}

__global__ void scan_final(const int* __restrict__ deg, const int* __restrict__ bsum,
                           int* __restrict__ off, int n) {
  __shared__ int ws[4];
  int b = blockIdx.x, t = threadIdx.x, lane = t & 63, w = t >> 6;
  int base = b * 1024 + t * 4;
  int v[4];
  #pragma unroll
  for (int k = 0; k < 4; ++k) v[k] = (base + k < n) ? deg[base + k] : 0;
  int tsum = v[0] + v[1] + v[2] + v[3];
  int incl = tsum;
  #pragma unroll
  for (int d = 1; d < 64; d <<= 1) { int y = __shfl_up(incl, d); if (lane >= d) incl += y; }
  if (lane == 63) ws[w] = incl;
  __syncthreads();
  int woff = 0;
  for (int j = 0; j < w; ++j) woff += ws[j];
  int run = bsum[b] + woff + (incl - tsum);
  #pragma unroll
  for (int k = 0; k < 4; ++k) {
    if (base + k < n) off[base + k] = run;
    run += v[k];
  }
}

__global__ void fillCSR(const int* __restrict__ ni, const int* __restrict__ ei,
                        const int* __restrict__ noff, const int* __restrict__ eoff,
                        int* __restrict__ ncur, int* __restrict__ ecur,
                        int* __restrict__ node_edge, int* __restrict__ edge_node) {
  int i = blockIdx.x * 256 + threadIdx.x;
  if (i < NNZ_) {
    int n = ni[i], e = ei[i];
    int pe = eoff[e] + atomicAdd(&ecur[e], 1);
    edge_node[pe] = n;
    int pn = noff[n] + atomicAdd(&ncur[n], 1);
    node_edge[pn] = e;
  }
}

__global__ void invdeg(const int* __restrict__ nd, const int* __restrict__ ed,
                       float* __restrict__ Dinv, float* __restrict__ Binv) {
  int i = blockIdx.x * 256 + threadIdx.x;
  if (i < N_NODES) { int d = nd[i]; Dinv[i] = d > 0 ? 1.f / (float)d : 0.f; }
  if (i < N_EDGES) { int d = ed[i]; Binv[i] = d > 0 ? 1.f / (float)d : 0.f; }
}

// W [K][N] fp32 -> WT [N][K] bf16 (all 3 layers, z = layer)
__global__ void convertWT(const float* __restrict__ W0, const float* __restrict__ W1,
                          const float* __restrict__ W2, short* __restrict__ WT3) {
  __shared__ float tile[64][65];
  const float* Wm = (blockIdx.z == 0) ? W0 : (blockIdx.z == 1) ? W1 : W2;
  short* WT = WT3 + (size_t)blockIdx.z * C_DIM * C_DIM;
  int tx = threadIdx.x & 63, ty = threadIdx.x >> 6;  // ty 0..3
  int kb = blockIdx.x * 64, nb = blockIdx.y * 64;
  #pragma unroll
  for (int j = 0; j < 64; j += 4)
    tile[j + ty][tx] = Wm[(size_t)(kb + j + ty) * C_DIM + nb + tx];
  __syncthreads();
  #pragma unroll
  for (int j = 0; j < 64; j += 4)
    WT[(size_t)(nb + j + ty) * C_DIM + kb + tx] = f2bf(tile[tx][j + ty]);
}

// ---------------- convertX: fp32 -> bf16 column-blocked [2][N][512] ----------------
__global__ void convertX(const float* __restrict__ X, short* __restrict__ Hbf) {
  size_t idx = ((size_t)blockIdx.x * 256 + threadIdx.x) * 8;
  int node = (int)(idx >> 10);
  int c = (int)(idx & 1023);
  int half = c >> 9, off = c & 511;
  float v[8];
  *(f32x4*)&v[0] = *(const f32x4*)&X[idx];
  *(f32x4*)&v[4] = *(const f32x4*)&X[idx + 4];
  bf16x8 ov;
  #pragma unroll
  for (int j = 0; j < 8; ++j) ov[j] = f2bf(v[j]);
  *(bf16x8*)&Hbf[((size_t)half * N_NODES + node) * HALF_C + off] = ov;
}

// ---------------- phaseA v3: one (edge, half) per 64-thread wave, blocked source,
//                  fused BN+ReLU ----------------
template <int BN>
__global__ __launch_bounds__(64) void phaseA_bn3(
    const short* __restrict__ Hbf, const int* __restrict__ eoff,
    const int* __restrict__ enode, const float* __restrict__ Binv,
    const float* __restrict__ sc, const float* __restrict__ sh,
    short* __restrict__ Mbf) {
  int t = threadIdx.x;            // 0..63
  int e = blockIdx.x;
  int half = blockIdx.y;
  int off = t * 8;                // col within half
  int gc = half * HALF_C + off;   // global col
  if (e >= N_EDGES) {
    bf16x8 z = {0, 0, 0, 0, 0, 0, 0, 0};
    *(bf16x8*)&Mbf[(size_t)e * C_DIM + gc] = z;
    return;
  }
  const short* __restrict__ src = Hbf + (size_t)half * N_NODES * HALF_C;
  float scl[8], shf[8];
  if (BN) {
    *(f32x4*)&scl[0] = *(const f32x4*)&sc[gc];
    *(f32x4*)&scl[4] = *(const f32x4*)&sc[gc + 4];
    *(f32x4*)&shf[0] = *(const f32x4*)&sh[gc];
    *(f32x4*)&shf[4] = *(const f32x4*)&sh[gc + 4];
  }
  int beg = eoff[e], end = eoff[e + 1];
  float a0[8] = {0, 0, 0, 0, 0, 0, 0, 0};
  float a1[8] = {0, 0, 0, 0, 0, 0, 0, 0};
  int i = beg;
  for (; i + 3 < end; i += 4) {
    int n0 = enode[i], n1 = enode[i + 1], n2 = enode[i + 2], n3 = enode[i + 3];
    bf16x8 v0 = *(const bf16x8*)&src[(size_t)n0 * HALF_C + off];
    bf16x8 v1 = *(const bf16x8*)&src[(size_t)n1 * HALF_C + off];
    bf16x8 v2 = *(const bf16x8*)&src[(size_t)n2 * HALF_C + off];
    bf16x8 v3 = *(const bf16x8*)&src[(size_t)n3 * HALF_C + off];
    #pragma unroll
    for (int j = 0; j < 8; ++j) {
      float f0 = bf2f(v0[j]), f1 = bf2f(v1[j]);
      float f2 = bf2f(v2[j]), f3 = bf2f(v3[j]);
      if (BN) {
        f0 = fmaxf(f0 * scl[j] + shf[j], 0.f);
        f1 = fmaxf(f1 * scl[j] + shf[j], 0.f);
        f2 = fmaxf(f2 * scl[j] + shf[j], 0.f);
        f3 = fmaxf(f3 * scl[j] + shf[j], 0.f);
      }
      a0[j] += f0 + f2;
      a1[j] += f1 + f3;
    }
  }
  for (; i < end; ++i) {
    bf16x8 v = *(const bf16x8*)&src[(size_t)enode[i] * HALF_C + off];
    #pragma unroll
    for (int j = 0; j < 8; ++j) {
      float f = bf2f(v[j]);
      if (BN) f = fmaxf(f * scl[j] + shf[j], 0.f);
      a0[j] += f;
    }
  }
  float bi = Binv[e];
  bf16x8 ov;
  #pragma unroll
  for (int j = 0; j < 8; ++j) ov[j] = f2bf((a0[j] + a1[j]) * bi);
  *(bf16x8*)&Mbf[(size_t)e * C_DIM + gc] = ov;
}

// ---------------- GEMM: C[E_PAD,1024]bf16 = A[E_PAD,1024]bf16 x BT[1024,1024]bf16 ----------------
__global__ __launch_bounds__(256) void gemm_bf16(const short* __restrict__ A,
                                                 const short* __restrict__ BT,
                                                 short* __restrict__ Cc) {
  __shared__ __align__(16) short As[2][128 * 32];
  __shared__ __align__(16) short Bs[2][128 * 32];
  const int tid = threadIdx.x;
  const int w = tid >> 6;
  const int lane = tid & 63;
  const int bm = blockIdx.x, bn = blockIdx.y;
  const int wr = w >> 1, wc = w & 1;
  const int fr = lane & 15, kg = lane >> 4;
  const int qa = w * 2;
  const int srow = lane >> 2;        // 0..15
  const int skof = (lane & 3) * 8;   // 0,8,16,24

  f32x4 acc[4][4] = {};

  auto stage = [&](int ks, int buf) {
    #pragma unroll
    for (int c2 = 0; c2 < 2; ++c2) {
      int q = qa + c2;
      int row = q * 16 + srow;
      size_t gA = (size_t)(bm * 128 + row) * C_DIM + ks * 32 + skof;
      size_t gB = (size_t)(bn * 128 + row) * C_DIM + ks * 32 + skof;
      __builtin_amdgcn_global_load_lds(
          (__attribute__((address_space(1))) void*)(A + gA),
          (__attribute__((address_space(3))) void*)(&As[buf][q * 512]), 16, 0, 0);
      __builtin_amdgcn_global_load_lds(
          (__attribute__((address_space(1))) void*)(BT + gB),
          (__attribute__((address_space(3))) void*)(&Bs[buf][q * 512]), 16, 0, 0);
    }
  };
  auto compute = [&](int buf) {
    bf16x8 a[4], b[4];
    #pragma unroll
    for (int m = 0; m < 4; ++m)
      a[m] = *(const bf16x8*)&As[buf][(wr * 64 + m * 16 + fr) * 32 + kg * 8];
    #pragma unroll
    for (int n = 0; n < 4; ++n)
      b[n] = *(const bf16x8*)&Bs[buf][(wc * 64 + n * 16 + fr) * 32 + kg * 8];
    #pragma unroll
    for (int m = 0; m < 4; ++m)
      #pragma unroll
      for (int n = 0; n < 4; ++n)
        acc[m][n] = __builtin_amdgcn_mfma_f32_16x16x32_bf16(a[m], b[n], acc[m][n], 0, 0, 0);
  };

  stage(0, 0);
  __syncthreads();
  for (int ks = 0; ks < 31; ++ks) {
    stage(ks + 1, (ks + 1) & 1);
    compute(ks & 1);
    __syncthreads();
  }
  compute(1);

  const int row0 = bm * 128 + wr * 64 + kg * 4;
  const int col0 = bn * 128 + wc * 64 + fr;
  #pragma unroll
  for (int m = 0; m < 4; ++m) {
    #pragma unroll
    for (int n = 0; n < 4; ++n) {
      int r = row0 + m * 16, cc = col0 + n * 16;
      #pragma unroll
      for (int j = 0; j < 4; ++j)
        Cc[(size_t)(r + j) * C_DIM + cc] = f2bf(acc[m][n][j]);
    }
  }
}

// ---------------- phaseB fused with BN stats, grid-stride, 4-deep MLP,
//                  writes Hp in column-blocked layout ----------------
__global__ void phaseB_fused3(const short* __restrict__ M, const int* __restrict__ noff,
                              const int* __restrict__ nedge, const float* __restrict__ Dinv,
                              const float* __restrict__ bias, short* __restrict__ Hp,
                              float* __restrict__ ps, float* __restrict__ pq) {
  int t = threadIdx.x;
  int c = t * 4;
  int half = c >> 9, off = c & 511;
  short* __restrict__ Hdst = Hp + (size_t)half * N_NODES * HALF_C;
  int b = blockIdx.x;
  f32x4 bias4 = *(const f32x4*)&bias[c];
  f32x4 bsum = {0.f, 0.f, 0.f, 0.f}, bsq = {0.f, 0.f, 0.f, 0.f};
  for (int n = b; n < N_NODES; n += PB_BLOCKS) {
    int beg = noff[n], end = noff[n + 1];
    float a0[4] = {0, 0, 0, 0}, a1[4] = {0, 0, 0, 0};
    int i = beg;
    for (; i + 3 < end; i += 4) {
      int e0 = nedge[i], e1 = nedge[i + 1], e2 = nedge[i + 2], e3 = nedge[i + 3];
      bf16x4 v0 = *(const bf16x4*)&M[(size_t)e0 * C_DIM + c];
      bf16x4 v1 = *(const bf16x4*)&M[(size_t)e1 * C_DIM + c];
      bf16x4 v2 = *(const bf16x4*)&M[(size_t)e2 * C_DIM + c];
      bf16x4 v3 = *(const bf16x4*)&M[(size_t)e3 * C_DIM + c];
      #pragma unroll
      for (int j = 0; j < 4; ++j) {
        a0[j] += bf2f(v0[j]) + bf2f(v2[j]);
        a1[j] += bf2f(v1[j]) + bf2f(v3[j]);
      }
    }
    for (; i < end; ++i) {
      bf16x4 v = *(const bf16x4*)&M[(size_t)nedge[i] * C_DIM + c];
      #pragma unroll
      for (int j = 0; j < 4; ++j) a0[j] += bf2f(v[j]);
    }
    float di = Dinv[n];
    bf16x4 ob;
    f32x4 orr;
    #pragma unroll
    for (int j = 0; j < 4; ++j) {
      float o = (a0[j] + a1[j]) * di + bias4[j];
      ob[j] = f2bf(o);
      orr[j] = bf2f(ob[j]);     // stats on stored (rounded) values
    }
    *(bf16x4*)&Hdst[(size_t)n * HALF_C + off] = ob;
    bsum += orr;
    bsq += orr * orr;
  }
  *(f32x4*)&ps[(size_t)b * C_DIM + c] = bsum;
  *(f32x4*)&pq[(size_t)b * C_DIM + c] = bsq;
}

// reduce [PB_BLOCKS][1024] -> [8][1024], coalesced
__global__ void reduceP(const float* __restrict__ ps, const float* __restrict__ pq,
                        float* __restrict__ ps2, float* __restrict__ pq2) {
  int i = blockIdx.x;            // 0..7
  int c = blockIdx.y * 256 + threadIdx.x;
  float s = 0.f, q = 0.f;
  for (int p = i * 256; p < (i + 1) * 256; ++p) {
    s += ps[(size_t)p * C_DIM + c];
    q += pq[(size_t)p * C_DIM + c];
  }
  ps2[(size_t)i * C_DIM + c] = s;
  pq2[(size_t)i * C_DIM + c] = q;
}

__global__ void bnfinal2(const float* __restrict__ ps2, const float* __restrict__ pq2,
                         const float* __restrict__ g, const float* __restrict__ be,
                         float* __restrict__ scale, float* __restrict__ shift) {
  int c = blockIdx.x * 256 + threadIdx.x;
  float s = 0.f, q = 0.f;
  #pragma unroll
  for (int p = 0; p < 8; ++p) {
    s += ps2[(size_t)p * C_DIM + c];
    q += pq2[(size_t)p * C_DIM + c];
  }
  const float invN = 1.f / (float)N_NODES;
  float mu = s * invN;
  float var = q * invN - mu * mu;
  float rs = rsqrtf(var + BN_EPS);
  float scl = g[c] * rs;
  scale[c] = scl;
  shift[c] = be[c] - mu * scl;
}

// ---------------- final: per-row BN+ReLU+dot from blocked bf16 H_pre ----------------
__global__ void finaldot_bf(const short* __restrict__ Hp, const float* __restrict__ sc,
                            const float* __restrict__ sh, const float* __restrict__ Wfc,
                            float* __restrict__ rows) {
  int row = blockIdx.x * 4 + (threadIdx.x >> 6);
  int lane = threadIdx.x & 63;
  if (row >= N_NODES) return;
  float s = 0.f;
  #pragma unroll
  for (int j = 0; j < 2; ++j) {
    int c = j * HALF_C + lane * 8;
    bf16x8 v = *(const bf16x8*)&Hp[((size_t)j * N_NODES + row) * HALF_C + lane * 8];
    float a[8], b[8], w[8];
    *(f32x4*)&a[0] = *(const f32x4*)&sc[c];
    *(f32x4*)&a[4] = *(const f32x4*)&sc[c + 4];
    *(f32x4*)&b[0] = *(const f32x4*)&sh[c];
    *(f32x4*)&b[4] = *(const f32x4*)&sh[c + 4];
    *(f32x4*)&w[0] = *(const f32x4*)&Wfc[c];
    *(f32x4*)&w[4] = *(const f32x4*)&Wfc[c + 4];
    #pragma unroll
    for (int k = 0; k < 8; ++k)
      s += fmaxf(bf2f(v[k]) * a[k] + b[k], 0.f) * w[k];
  }
  #pragma unroll
  for (int off = 32; off; off >>= 1) s += __shfl_down(s, off);
  if (lane == 0) rows[row] = s;
}

// batch is sorted -> LDS bins then few global atomics
__global__ void poolbin(const float* __restrict__ rows, const int* __restrict__ batch,
                        float* __restrict__ gsum, int* __restrict__ gcnt) {
  __shared__ float bins[N_GRAPHS];
  __shared__ int cbin[N_GRAPHS];
  int t = threadIdx.x;
  if (t < N_GRAPHS) { bins[t] = 0.f; cbin[t] = 0; }
  __syncthreads();
  int quad = blockIdx.x * 256 + t;            // 12500 quads = 50000 rows
  if (quad * 4 < N_NODES) {
    f32x4 r = *(const f32x4*)&rows[quad * 4];
    int4 bi = *(const int4*)&batch[quad * 4];
    int g0 = bi.x;
    float acc = r[0];
    int cc = 1;
    int gn[3] = {bi.y, bi.z, bi.w};
    float rn[3] = {r[1], r[2], r[3]};
    #pragma unroll
    for (int j = 0; j < 3; ++j) {
      if (gn[j] == g0) { acc += rn[j]; ++cc; }
      else {
        atomicAdd(&bins[g0], acc);
        atomicAdd(&cbin[g0], cc);
        g0 = gn[j]; acc = rn[j]; cc = 1;
      }
    }
    atomicAdd(&bins[g0], acc);
    atomicAdd(&cbin[g0], cc);
  }
  __syncthreads();
  if (t < N_GRAPHS && cbin[t] > 0) {
    atomicAdd(&gsum[t], bins[t]);
    atomicAdd(&gcnt[t], cbin[t]);
  }
}

__global__ void finalout(const float* __restrict__ gsum, const int* __restrict__ gcnt,
                         const float* __restrict__ bfc, float* __restrict__ out) {
  int g = threadIdx.x;
  float cnt = (float)(gcnt[g] > 0 ? gcnt[g] : 1);
  float v = gsum[g] / cnt + bfc[0];
  out[g] = 1.f / (1.f + expf(-v));
}

// ---------------- host launcher ----------------
extern "C" void kernel_launch(void* const* d_in, const int* in_sizes, int n_in,
                              void* d_out, int out_size, void* d_ws, size_t ws_size,
                              hipStream_t stream) {
  const float* x        = (const float*)d_in[0];
  const int*   node_idx = (const int*)d_in[1];
  const int*   hedge_idx= (const int*)d_in[2];
  const int*   batch    = (const int*)d_in[3];
  const float* W[3]  = {(const float*)d_in[4], (const float*)d_in[6], (const float*)d_in[8]};
  const float* bb[3] = {(const float*)d_in[5], (const float*)d_in[7], (const float*)d_in[9]};
  const float* g[3]  = {(const float*)d_in[10], (const float*)d_in[12], (const float*)d_in[14]};
  const float* be[3] = {(const float*)d_in[11], (const float*)d_in[13], (const float*)d_in[15]};
  const float* Wfc   = (const float*)d_in[16];
  const float* bfc   = (const float*)d_in[17];
  float* out = (float*)d_out;

  char* ws = (char*)d_ws;
  size_t o = 0;
  auto take = [&](size_t bytes) -> char* {
    char* p = ws + o;
    o += (bytes + 255) & ~(size_t)255;
    return p;
  };
  short* Xbf  = (short*)take((size_t)N_NODES * C_DIM * 2);  // layer-0 source, blocked
  short* Hp   = (short*)take((size_t)N_NODES * C_DIM * 2);  // pre-BN activations, blocked
  short* Mbf  = (short*)take((size_t)E_PAD * C_DIM * 2);    // edge features bf16
  short* WT3  = (short*)take((size_t)3 * C_DIM * C_DIM * 2);
  short* Mw   = (short*)take((size_t)E_PAD * C_DIM * 2);    // (m*Binv) @ W, bf16
  char*  zgrp = take(432512);
  int*   node_deg = (int*)zgrp;
  int*   edge_deg = (int*)(zgrp + 200000);
  int*   node_cur = (int*)(zgrp + 216000);
  int*   edge_cur = (int*)(zgrp + 416000);
  float* gsum     = (float*)(zgrp + 432000);
  int*   gcnt     = (int*)(zgrp + 432256);
  int* node_off  = (int*)take((N_NODES + 1) * 4);
  int* edge_off  = (int*)take((N_EDGES + 1) * 4);
  int* node_edge = (int*)take((size_t)NNZ_ * 4);
  int* edge_node = (int*)take((size_t)NNZ_ * 4);
  int* bsumN = (int*)take(256);
  int* bsumE = (int*)take(256);
  float* Dinv = (float*)take(N_NODES * 4);
  float* Binv = (float*)take(N_EDGES * 4);
  float* scale = (float*)take(4096);
  float* shift = (float*)take(4096);
  float* part_s = (float*)take((size_t)PB_BLOCKS * C_DIM * 4);
  float* part_q = (float*)take((size_t)PB_BLOCKS * C_DIM * 4);
  float* ps2    = (float*)take((size_t)8 * C_DIM * 4);
  float* pq2    = (float*)take((size_t)8 * C_DIM * 4);
  float* rows   = (float*)take((size_t)N_NODES * 4);

  // zero atomic accumulators (must be re-zeroed every call)
  hipMemsetAsync(zgrp, 0, 432512, stream);

  // degree + CSR build (parallel 3-stage scans)
  const int nbN = (N_NODES + 1023) / 1024;   // 49
  const int nbE = (N_EDGES + 1023) / 1024;   // 4
  countDeg<<<(NNZ_ + 255) / 256, 256, 0, stream>>>(node_idx, hedge_idx, node_deg, edge_deg);
  scan_part<<<nbE, 256, 0, stream>>>(edge_deg, bsumE, N_EDGES);
  scan_mid<<<1, 64, 0, stream>>>(bsumE, nbE, edge_off, N_EDGES);
  scan_final<<<nbE, 256, 0, stream>>>(edge_deg, bsumE, edge_off, N_EDGES);
  scan_part<<<nbN, 256, 0, stream>>>(node_deg, bsumN, N_NODES);
  scan_mid<<<1, 64, 0, stream>>>(bsumN, nbN, node_off, N_NODES);
  scan_final<<<nbN, 256, 0, stream>>>(node_deg, bsumN, node_off, N_NODES);
  fillCSR<<<(NNZ_ + 255) / 256, 256, 0, stream>>>(node_idx, hedge_idx, node_off, edge_off,
                                                  node_cur, edge_cur, node_edge, edge_node);
  invdeg<<<(N_NODES + 255) / 256, 256, 0, stream>>>(node_deg, edge_deg, Dinv, Binv);

  const int cgrid = (int)((size_t)N_NODES * C_DIM / (8 * 256));  // 25000
  convertX<<<cgrid, 256, 0, stream>>>(x, Xbf);
  convertWT<<<dim3(16, 16, 3), 256, 0, stream>>>(W[0], W[1], W[2], WT3);
  for (int L = 0; L < 3; ++L) {
    const short* src = (L == 0) ? Xbf : Hp;
    if (L == 0)
      phaseA_bn3<0><<<dim3(E_PAD, 2), 64, 0, stream>>>(src, edge_off, edge_node, Binv,
                                                       nullptr, nullptr, Mbf);
    else
      phaseA_bn3<1><<<dim3(E_PAD, 2), 64, 0, stream>>>(src, edge_off, edge_node, Binv,
                                                       scale, shift, Mbf);
    gemm_bf16<<<dim3(E_PAD / 128, C_DIM / 128), 256, 0, stream>>>(
        Mbf, WT3 + (size_t)L * C_DIM * C_DIM, Mw);
    phaseB_fused3<<<PB_BLOCKS, 256, 0, stream>>>(Mw, node_off, node_edge, Dinv, bb[L],
                                                 Hp, part_s, part_q);
    reduceP<<<dim3(8, 4), 256, 0, stream>>>(part_s, part_q, ps2, pq2);
    bnfinal2<<<4, 256, 0, stream>>>(ps2, pq2, g[L], be[L], scale, shift);
  }
  finaldot_bf<<<(N_NODES + 3) / 4, 256, 0, stream>>>(Hp, scale, shift, Wfc, rows);
  poolbin<<<(N_NODES / 4 + 255) / 256, 256, 0, stream>>>(rows, batch, gsum, gcnt);
  finalout<<<1, 64, 0, stream>>>(gsum, gcnt, bfc, out);
}